// Round 1
// baseline (972.010 us; speedup 1.0000x reference)
//
#include <hip/hip_runtime.h>
#include <math.h>

#define NH 16
#define TT 1024
#define CC 1024
#define DD 64
#define MM 8192

// ---------------- helpers ----------------
__device__ __forceinline__ float wredsum(float x) {
#pragma unroll
  for (int o = 32; o; o >>= 1) x += __shfl_xor(x, o);
  return x;
}
__device__ __forceinline__ float wredmax(float x) {
#pragma unroll
  for (int o = 32; o; o >>= 1) x = fmaxf(x, __shfl_xor(x, o));
  return x;
}

// insert (d,i) into ascending (d,i)-lexicographic top-4 list
__device__ __forceinline__ void ins4(float d, int i, float vd[4], int vi[4]) {
  if (d < vd[3] || (d == vd[3] && i < vi[3])) {
    vd[3] = d; vi[3] = i;
#pragma unroll
    for (int s = 3; s > 0; --s) {
      bool sw = (vd[s] < vd[s - 1]) || (vd[s] == vd[s - 1] && vi[s] < vi[s - 1]);
      if (sw) {
        float td = vd[s]; vd[s] = vd[s - 1]; vd[s - 1] = td;
        int ti = vi[s]; vi[s] = vi[s - 1]; vi[s - 1] = ti;
      }
    }
  }
}

// ---------------- generic C = scale*(A@B^T) + bias ----------------
// A: M x K (lda), B: N x K (ldb), C: M x N (ldc). 64x64 tile, BK=16, 4x4/thread.
__global__ void __launch_bounds__(256) gemm_abt(
    const float* __restrict__ A, const float* __restrict__ B,
    float* __restrict__ Cp, const float* __restrict__ bias,
    int K, int lda, int ldb, int ldc,
    long long aB, long long bB, long long cB, float scale)
{
  A  += (size_t)blockIdx.z * aB;
  B  += (size_t)blockIdx.z * bB;
  Cp += (size_t)blockIdx.z * cB;
  int m0 = blockIdx.y * 64, n0 = blockIdx.x * 64;
  int tid = threadIdx.x, tx = tid & 15, ty = tid >> 4;
  __shared__ float As[64][17], Bs[64][17];
  float acc[4][4] = {};
  for (int k0 = 0; k0 < K; k0 += 16) {
    __syncthreads();
    for (int i = tid; i < 1024; i += 256) {
      int r = i >> 4, c = i & 15;
      As[r][c] = A[(size_t)(m0 + r) * lda + k0 + c];
      Bs[r][c] = B[(size_t)(n0 + r) * ldb + k0 + c];
    }
    __syncthreads();
#pragma unroll
    for (int kk = 0; kk < 16; ++kk) {
      float a[4], b[4];
#pragma unroll
      for (int i = 0; i < 4; ++i) a[i] = As[ty * 4 + i][kk];
#pragma unroll
      for (int j = 0; j < 4; ++j) b[j] = Bs[tx * 4 + j][kk];
#pragma unroll
      for (int i = 0; i < 4; ++i)
#pragma unroll
        for (int j = 0; j < 4; ++j) acc[i][j] = fmaf(a[i], b[j], acc[i][j]);
    }
  }
#pragma unroll
  for (int i = 0; i < 4; ++i)
#pragma unroll
    for (int j = 0; j < 4; ++j) {
      int m = m0 + ty * 4 + i, n = n0 + tx * 4 + j;
      float v = acc[i][j] * scale;
      if (bias) v += bias[n];
      Cp[(size_t)m * ldc + n] = v;
    }
}

// ---------------- causal softmax, one wave per (h, i) row ----------------
__global__ void __launch_bounds__(256) softmax_causal(float* __restrict__ att) {
  int gw = (blockIdx.x * 256 + threadIdx.x) >> 6;
  int lane = threadIdx.x & 63;
  int h = gw >> 10, i = gw & 1023;
  float* row = att + ((size_t)h << 20) + ((size_t)i << 10);
  float e[16];
  float mx = -INFINITY;
#pragma unroll
  for (int c = 0; c < 16; ++c) {
    int j = lane + (c << 6);
    float x = (j <= i) ? row[j] : -INFINITY;
    e[c] = x;
    mx = fmaxf(mx, x);
  }
  mx = wredmax(mx);
  float sum = 0.f;
#pragma unroll
  for (int c = 0; c < 16; ++c) {
    int j = lane + (c << 6);
    float v = (j <= i) ? __expf(e[c] - mx) : 0.f;
    e[c] = v;
    sum += v;
  }
  sum = wredsum(sum);
  float inv = 1.0f / sum;
#pragma unroll
  for (int c = 0; c < 16; ++c) row[lane + (c << 6)] = e[c] * inv;
}

// ---------------- ||K_store[h,m]||^2 ----------------
__global__ void __launch_bounds__(256) knorm_kernel(const float* __restrict__ ks,
                                                    float* __restrict__ kn) {
  int m = blockIdx.x * 256 + threadIdx.x;  // 0 .. 16*8192-1
  const float4* p = (const float4*)(ks + (size_t)m * DD);
  float s = 0.f;
#pragma unroll
  for (int j = 0; j < 16; ++j) {
    float4 v = p[j];
    s = fmaf(v.x, v.x, s); s = fmaf(v.y, v.y, s);
    s = fmaf(v.z, v.z, s); s = fmaf(v.w, v.w, s);
  }
  kn[m] = s;
}

// ---------------- fused distance + top-4 ----------------
// block = 256 threads handles 16 t-rows of one head; thread = (t_local=tid>>4, m_local=tid&15)
__global__ void __launch_bounds__(256) topk_kernel(
    const float* __restrict__ qkv, const float* __restrict__ kstore,
    const float* __restrict__ knorm, int* __restrict__ idx_out)
{
  int h = blockIdx.y, t0 = blockIdx.x * 16;
  int tid = threadIdx.x;
  int tl = tid >> 4, ml = tid & 15;
  __shared__ __align__(16) float ks[64][68];   // K_store tile (64 m-rows)
  __shared__ float kn[64];
  __shared__ float cd_s[16][16][4];
  __shared__ int   ci_s[16][16][4];

  // this thread's k-row (t = t0+tl) into registers
  const float* krow = qkv + (size_t)(t0 + tl) * (3 * CC) + CC + h * DD;
  float4 kreg[16];
#pragma unroll
  for (int j4 = 0; j4 < 16; ++j4) kreg[j4] = *(const float4*)&krow[j4 * 4];

  float bd[4] = {3.0e38f, 3.0e38f, 3.0e38f, 3.0e38f};
  int   bi[4] = {-1, -1, -1, -1};
  const float* KH = kstore + (size_t)h * MM * DD;
  const float* KN = knorm + (size_t)h * MM;

  for (int mt = 0; mt < MM; mt += 64) {
    __syncthreads();
    // load 64x64 K_store tile (1024 float4, 4 per thread), coalesced
    for (int f4 = tid; f4 < 1024; f4 += 256) {
      int m = f4 >> 4, c4 = f4 & 15;
      *(float4*)&ks[m][c4 * 4] = *(const float4*)&KH[(size_t)(mt + m) * DD + c4 * 4];
    }
    if (tid < 64) kn[tid] = KN[mt + tid];
    __syncthreads();
#pragma unroll
    for (int s = 0; s < 4; ++s) {
      int m = ml + s * 16;
      float dot = 0.f;
#pragma unroll
      for (int j4 = 0; j4 < 16; ++j4) {
        float4 a = kreg[j4];
        float4 b = *(const float4*)&ks[m][j4 * 4];
        dot = fmaf(a.x, b.x, dot); dot = fmaf(a.y, b.y, dot);
        dot = fmaf(a.z, b.z, dot); dot = fmaf(a.w, b.w, dot);
      }
      // score = ||K||^2 - 2 k.K  (the +||k||^2 shift doesn't change ordering)
      ins4(kn[m] - 2.0f * dot, mt + m, bd, bi);
    }
  }
#pragma unroll
  for (int s = 0; s < 4; ++s) { cd_s[tl][ml][s] = bd[s]; ci_s[tl][ml][s] = bi[s]; }
  __syncthreads();
  if (tid < 16) {
    int t = tid;
    float fd[4]; int fi[4];
#pragma unroll
    for (int s = 0; s < 4; ++s) { fd[s] = cd_s[t][0][s]; fi[s] = ci_s[t][0][s]; }
    for (int w = 1; w < 16; ++w)
#pragma unroll
      for (int s = 0; s < 4; ++s) ins4(cd_s[t][w][s], ci_s[t][w][s], fd, fi);
    int* o = idx_out + ((size_t)h * TT + (t0 + t)) * 4;
#pragma unroll
    for (int s = 0; s < 4; ++s) o[s] = fi[s];
  }
}

// ---------------- kNN attend: one wave per (h,t) ----------------
__global__ void __launch_bounds__(256) knn_attend(
    const float* __restrict__ qkv, const float* __restrict__ att,
    const int* __restrict__ idx, const float* __restrict__ kstore,
    const float* __restrict__ vstore, float* __restrict__ vnew)
{
  int gw = (blockIdx.x * 256 + threadIdx.x) >> 6;
  int lane = threadIdx.x & 63;
  int h = gw >> 10, t = gw & 1023;
  const float* base = qkv + (size_t)t * (3 * CC) + h * DD;
  float q = base[lane];
  float k = base[CC + lane];
  float v = base[2 * CC + lane];
  float attlast = att[((size_t)h << 20) + (1023u << 10) + t];
  bool sel = attlast >= (1.0f / 8192.0f);
  const int* ix = idx + ((size_t)h * TT + t) * 4;

  float attf[5], vf[5];
  attf[0] = wredsum(q * k) * 0.125f;
  vf[0] = v;
#pragma unroll
  for (int s = 1; s < 5; ++s) {
    int m = ix[s - 1];
    const float* kp = kstore + ((size_t)h * MM + m) * DD;
    const float* vp = vstore + ((size_t)h * MM + m) * DD;
    attf[s] = wredsum(q * kp[lane]) * 0.125f;
    vf[s] = vp[lane];
  }
  float mx = attf[0];
#pragma unroll
  for (int s = 1; s < 5; ++s) mx = fmaxf(mx, attf[s]);
  float w[5], sum = 0.f;
#pragma unroll
  for (int s = 0; s < 5; ++s) { w[s] = __expf(attf[s] - mx); sum += w[s]; }
  float inv = 1.0f / sum;
  float vals = 0.f;
#pragma unroll
  for (int s = 0; s < 5; ++s) vals = fmaf(w[s] * inv, vf[s], vals);
  float r = 0.5f * vals + 0.5f * v;
  vnew[(size_t)h * TT * DD + (size_t)t * DD + lane] = sel ? r : v;
}

// ---------------- y[t, h*64+c] = sum_j att[h,t,j] * vnew[h,j,c] ----------------
__global__ void __launch_bounds__(256) gemm_att_v(
    const float* __restrict__ att, const float* __restrict__ vnew,
    float* __restrict__ y)
{
  int h = blockIdx.y;
  int m0 = blockIdx.x * 64;
  const float* A  = att + ((size_t)h << 20);
  const float* Bv = vnew + ((size_t)h << 16);
  float* Cp = y + h * DD;
  int tid = threadIdx.x, tx = tid & 15, ty = tid >> 4;
  __shared__ float As[64][17], Bs[16][65];
  float acc[4][4] = {};
  for (int k0 = 0; k0 < TT; k0 += 16) {
    __syncthreads();
    for (int i = tid; i < 1024; i += 256) {
      int r = i >> 4, c = i & 15;
      As[r][c] = A[(size_t)(m0 + r) * TT + k0 + c];
    }
    for (int i = tid; i < 1024; i += 256) {
      int r = i >> 6, c = i & 63;
      Bs[r][c] = Bv[(size_t)(k0 + r) * DD + c];
    }
    __syncthreads();
#pragma unroll
    for (int kk = 0; kk < 16; ++kk) {
      float a[4], b[4];
#pragma unroll
      for (int i = 0; i < 4; ++i) a[i] = As[ty * 4 + i][kk];
#pragma unroll
      for (int j = 0; j < 4; ++j) b[j] = Bs[kk][tx * 4 + j];
#pragma unroll
      for (int i = 0; i < 4; ++i)
#pragma unroll
        for (int j = 0; j < 4; ++j) acc[i][j] = fmaf(a[i], b[j], acc[i][j]);
    }
  }
#pragma unroll
  for (int i = 0; i < 4; ++i)
#pragma unroll
    for (int j = 0; j < 4; ++j)
      Cp[(size_t)(m0 + ty * 4 + i) * CC + tx * 4 + j] = acc[i][j];
}

// ---------------- launch ----------------
extern "C" void kernel_launch(void* const* d_in, const int* in_sizes, int n_in,
                              void* d_out, int out_size, void* d_ws, size_t ws_size,
                              hipStream_t stream) {
  (void)in_sizes; (void)n_in; (void)out_size; (void)ws_size;
  const float* x  = (const float*)d_in[0];
  const float* Wa = (const float*)d_in[1];
  const float* ba = (const float*)d_in[2];
  const float* Wp = (const float*)d_in[3];
  const float* bp = (const float*)d_in[4];
  const float* Ks = (const float*)d_in[5];
  const float* Vs = (const float*)d_in[6];
  float* out = (float*)d_out;

  float* qkv   = (float*)d_ws;                       // 1024*3072
  float* att   = qkv + (size_t)TT * 3 * CC;          // 16*1024*1024
  float* vnew  = att + (size_t)NH * TT * TT;         // 16*1024*64
  float* y     = vnew + (size_t)NH * TT * DD;        // 1024*1024
  float* knorm = y + (size_t)TT * CC;                // 16*8192
  int*   idx   = (int*)(knorm + (size_t)NH * MM);    // 16*1024*4

  // 1) qkv = x @ Wa^T + ba
  hipLaunchKernelGGL(gemm_abt, dim3(3 * CC / 64, TT / 64, 1), dim3(256), 0, stream,
                     x, Wa, qkv, ba, CC, CC, CC, 3 * CC, 0LL, 0LL, 0LL, 1.0f);
  // 2) logits per head: att[h] = (q_h @ k_h^T) / 8
  hipLaunchKernelGGL(gemm_abt, dim3(TT / 64, TT / 64, NH), dim3(256), 0, stream,
                     qkv, qkv + CC, att, (const float*)nullptr,
                     DD, 3 * CC, 3 * CC, TT, 64LL, 64LL, (long long)TT * TT, 0.125f);
  // 3) causal softmax in place
  hipLaunchKernelGGL(softmax_causal, dim3(NH * TT / 4), dim3(256), 0, stream, att);
  // 4) key-store norms
  hipLaunchKernelGGL(knorm_kernel, dim3(NH * MM / 256), dim3(256), 0, stream, Ks, knorm);
  // 5) fused distances + top-4
  hipLaunchKernelGGL(topk_kernel, dim3(TT / 16, NH), dim3(256), 0, stream,
                     qkv, Ks, knorm, idx);
  // 6) kNN attention over {self} U top-4, blend, select
  hipLaunchKernelGGL(knn_attend, dim3(NH * TT / 4), dim3(256), 0, stream,
                     qkv, att, idx, Ks, Vs, vnew);
  // 7) y = att @ v_new   (written in (t, h*64+c) layout)
  hipLaunchKernelGGL(gemm_att_v, dim3(TT / 64, NH), dim3(256), 0, stream,
                     att, vnew, y);
  // 8) out = y @ Wp^T + bp
  hipLaunchKernelGGL(gemm_abt, dim3(CC / 64, TT / 64, 1), dim3(256), 0, stream,
                     y, Wp, out, bp, CC, CC, CC, CC, 0LL, 0LL, 0LL, 1.0f);
}

// Round 2
// 847.388 us; speedup vs baseline: 1.1471x; 1.1471x over previous
//
#include <hip/hip_runtime.h>
#include <math.h>

#define NH 16
#define TT 1024
#define CC 1024
#define DD 64
#define MM 8192

typedef __attribute__((ext_vector_type(8))) short short8;
typedef __attribute__((ext_vector_type(4))) float f32x4;

// ---------------- helpers ----------------
__device__ __forceinline__ float wredsum(float x) {
#pragma unroll
  for (int o = 32; o; o >>= 1) x += __shfl_xor(x, o);
  return x;
}
__device__ __forceinline__ float wredmax(float x) {
#pragma unroll
  for (int o = 32; o; o >>= 1) x = fmaxf(x, __shfl_xor(x, o));
  return x;
}

__device__ __forceinline__ unsigned int bf16rn(float x) {
  unsigned int u = __float_as_uint(x);
  return (u + 0x7fffu + ((u >> 16) & 1u)) >> 16;
}
__device__ __forceinline__ float bf16f(unsigned int h) {
  return __uint_as_float(h << 16);
}

// insert (d,i) into ascending (d,i)-lexicographic top-4 list
__device__ __forceinline__ void ins4(float d, int i, float vd[4], int vi[4]) {
  if (d < vd[3] || (d == vd[3] && i < vi[3])) {
    vd[3] = d; vi[3] = i;
#pragma unroll
    for (int s = 3; s > 0; --s) {
      bool sw = (vd[s] < vd[s - 1]) || (vd[s] == vd[s - 1] && vi[s] < vi[s - 1]);
      if (sw) {
        float td = vd[s]; vd[s] = vd[s - 1]; vd[s - 1] = td;
        int ti = vi[s]; vi[s] = vi[s - 1]; vi[s - 1] = ti;
      }
    }
  }
}

// ---------------- generic C = scale*(A@B^T) + bias ----------------
__global__ void __launch_bounds__(256) gemm_abt(
    const float* __restrict__ A, const float* __restrict__ B,
    float* __restrict__ Cp, const float* __restrict__ bias,
    int K, int lda, int ldb, int ldc,
    long long aB, long long bB, long long cB, float scale)
{
  A  += (size_t)blockIdx.z * aB;
  B  += (size_t)blockIdx.z * bB;
  Cp += (size_t)blockIdx.z * cB;
  int m0 = blockIdx.y * 64, n0 = blockIdx.x * 64;
  int tid = threadIdx.x, tx = tid & 15, ty = tid >> 4;
  __shared__ float As[64][17], Bs[64][17];
  float acc[4][4] = {};
  for (int k0 = 0; k0 < K; k0 += 16) {
    __syncthreads();
    for (int i = tid; i < 1024; i += 256) {
      int r = i >> 4, c = i & 15;
      As[r][c] = A[(size_t)(m0 + r) * lda + k0 + c];
      Bs[r][c] = B[(size_t)(n0 + r) * ldb + k0 + c];
    }
    __syncthreads();
#pragma unroll
    for (int kk = 0; kk < 16; ++kk) {
      float a[4], b[4];
#pragma unroll
      for (int i = 0; i < 4; ++i) a[i] = As[ty * 4 + i][kk];
#pragma unroll
      for (int j = 0; j < 4; ++j) b[j] = Bs[tx * 4 + j][kk];
#pragma unroll
      for (int i = 0; i < 4; ++i)
#pragma unroll
        for (int j = 0; j < 4; ++j) acc[i][j] = fmaf(a[i], b[j], acc[i][j]);
    }
  }
#pragma unroll
  for (int i = 0; i < 4; ++i)
#pragma unroll
    for (int j = 0; j < 4; ++j) {
      int m = m0 + ty * 4 + i, n = n0 + tx * 4 + j;
      float v = acc[i][j] * scale;
      if (bias) v += bias[n];
      Cp[(size_t)m * ldc + n] = v;
    }
}

// ---------------- causal softmax, one wave per (h, i) row ----------------
__global__ void __launch_bounds__(256) softmax_causal(float* __restrict__ att) {
  int gw = (blockIdx.x * 256 + threadIdx.x) >> 6;
  int lane = threadIdx.x & 63;
  int h = gw >> 10, i = gw & 1023;
  float* row = att + ((size_t)h << 20) + ((size_t)i << 10);
  float e[16];
  float mx = -INFINITY;
#pragma unroll
  for (int c = 0; c < 16; ++c) {
    int j = lane + (c << 6);
    float x = (j <= i) ? row[j] : -INFINITY;
    e[c] = x;
    mx = fmaxf(mx, x);
  }
  mx = wredmax(mx);
  float sum = 0.f;
#pragma unroll
  for (int c = 0; c < 16; ++c) {
    int j = lane + (c << 6);
    float v = (j <= i) ? __expf(e[c] - mx) : 0.f;
    e[c] = v;
    sum += v;
  }
  sum = wredsum(sum);
  float inv = 1.0f / sum;
#pragma unroll
  for (int c = 0; c < 16; ++c) row[lane + (c << 6)] = e[c] * inv;
}

// ---------------- convert K_store -> swizzled bf16 hi/lo + norms ----------------
// For (h,m,chunk c in 0..7): 8 bf16 stored at byte (h*MM+m)*128 + (c^(m&7))*16
__global__ void __launch_bounds__(256) convert_kernel(
    const float* __restrict__ ks, char* __restrict__ khi,
    char* __restrict__ klo, float* __restrict__ kn)
{
  int g = blockIdx.x * 256 + threadIdx.x;  // h*MM + m
  int m = g & (MM - 1);
  const float* src = ks + (size_t)g * DD;
  float nrm = 0.f;
  size_t rowb = (size_t)g * 128;
#pragma unroll
  for (int c = 0; c < 8; ++c) {
    float f[8];
#pragma unroll
    for (int j = 0; j < 8; ++j) {
      f[j] = src[c * 8 + j];
      nrm = fmaf(f[j], f[j], nrm);
    }
    uint4 hv, lv;
    unsigned int hw[4], lw[4];
#pragma unroll
    for (int p = 0; p < 4; ++p) {
      unsigned int h0 = bf16rn(f[2 * p]), h1 = bf16rn(f[2 * p + 1]);
      float r0 = f[2 * p] - bf16f(h0), r1 = f[2 * p + 1] - bf16f(h1);
      hw[p] = h0 | (h1 << 16);
      lw[p] = bf16rn(r0) | (bf16rn(r1) << 16);
    }
    hv.x = hw[0]; hv.y = hw[1]; hv.z = hw[2]; hv.w = hw[3];
    lv.x = lw[0]; lv.y = lw[1]; lv.z = lw[2]; lv.w = lw[3];
    size_t off = rowb + (size_t)(((c ^ (m & 7)) << 4));
    *(uint4*)(khi + off) = hv;
    *(uint4*)(klo + off) = lv;
  }
  kn[g] = nrm;
}

// ---------------- staging helpers (global -> LDS direct) ----------------
__device__ __forceinline__ void stage_seg16(const char* gsrc, char* ldst, int lane) {
  __builtin_amdgcn_global_load_lds(
      (const __attribute__((address_space(1))) unsigned int*)(gsrc + lane * 16),
      (__attribute__((address_space(3))) unsigned int*)ldst, 16, 0, 0);
}
__device__ __forceinline__ void stage_seg4(const char* gsrc, char* ldst, int lane) {
  __builtin_amdgcn_global_load_lds(
      (const __attribute__((address_space(1))) unsigned int*)(gsrc + lane * 4),
      (__attribute__((address_space(3))) unsigned int*)ldst, 4, 0, 0);
}

// ---------------- MFMA distance + top-4 ----------------
// grid 512: bid -> h = bid&15 (XCD locality), ttile = (bid>>4)&15, mhalf = bid>>8
// block 256 = 4 waves; wave w: wr=w>>1 (t half of 64), wc=w&1 (m half of 64)
#define BUFB 16640  // 16384 tile (khi 8K + klo 8K) + 256 knorm
__global__ void __launch_bounds__(256) topk_mfma(
    const float* __restrict__ qkv, const char* __restrict__ khi,
    const char* __restrict__ klo, const float* __restrict__ knorm,
    float* __restrict__ pd, int* __restrict__ pi)
{
  int bid = blockIdx.x;
  int h = bid & 15, ttile = (bid >> 4) & 15, mhalf = bid >> 8;
  int tid = threadIdx.x, lane = tid & 63, w = tid >> 6;
  int wr = w >> 1, wc = w & 1;
  int t0 = ttile * 64;
  __shared__ __align__(16) char smem[2 * BUFB + 4096];

  // ---- A fragments: this wave's 32 k-rows, split hi/lo, 2 k-halves ----
  short8 ahi[2][2], alo[2][2];  // [ts][kh]
#pragma unroll
  for (int ts = 0; ts < 2; ++ts) {
    const float* rowp =
        qkv + (size_t)(t0 + wr * 32 + ts * 16 + (lane & 15)) * (3 * CC) + CC + h * DD;
#pragma unroll
    for (int kh = 0; kh < 2; ++kh) {
      const float* p = rowp + kh * 32 + (lane >> 4) * 8;
#pragma unroll
      for (int j = 0; j < 8; ++j) {
        float a = p[j];
        unsigned int hb = bf16rn(a);
        float lr = a - bf16f(hb);
        ahi[ts][kh][j] = (short)hb;
        alo[ts][kh][j] = (short)bf16rn(lr);
      }
    }
  }

  const char* ghi = khi + ((size_t)h * MM + (size_t)mhalf * 4096) * 128;
  const char* glo = klo + ((size_t)h * MM + (size_t)mhalf * 4096) * 128;
  const char* gkn = (const char*)(knorm + (size_t)h * MM + (size_t)mhalf * 4096);

  float bd[2][4][4];
  int   bi_[2][4][4];
#pragma unroll
  for (int ts = 0; ts < 2; ++ts)
#pragma unroll
    for (int r = 0; r < 4; ++r)
#pragma unroll
      for (int s = 0; s < 4; ++s) { bd[ts][r][s] = 3.0e38f; bi_[ts][r][s] = -1; }

  // prologue stage tile 0
  {
    char* nb = smem;
#pragma unroll
    for (int i2 = 0; i2 < 4; ++i2) {
      int s = w * 4 + i2;
      const char* src = (s < 8) ? (ghi + s * 1024) : (glo + (s - 8) * 1024);
      stage_seg16(src, nb + s * 1024, lane);
    }
    if (w == 0) stage_seg4(gkn, nb + 16384, lane);
  }
  __syncthreads();

  int buf = 0;
  for (int it = 0; it < 64; ++it) {
    char* cb = smem + buf * BUFB;
    if (it < 63) {  // issue next-tile stage before compute (latency overlap)
      char* nb = smem + (buf ^ 1) * BUFB;
      const char* bh = ghi + (size_t)(it + 1) * 8192;
      const char* bl = glo + (size_t)(it + 1) * 8192;
#pragma unroll
      for (int i2 = 0; i2 < 4; ++i2) {
        int s = w * 4 + i2;
        const char* src = (s < 8) ? (bh + s * 1024) : (bl + (s - 8) * 1024);
        stage_seg16(src, nb + s * 1024, lane);
      }
      if (w == 0) stage_seg4(gkn + (size_t)(it + 1) * 256, nb + 16384, lane);
    }
    // B fragments (swizzled read)
    short8 bhif[2][2], blof[2][2];  // [ms][kh]
#pragma unroll
    for (int ms = 0; ms < 2; ++ms) {
      int mloc = wc * 32 + ms * 16 + (lane & 15);
#pragma unroll
      for (int kh = 0; kh < 2; ++kh) {
        int c = kh * 4 + (lane >> 4);
        int off = mloc * 128 + (((c ^ (mloc & 7)) << 4));
        bhif[ms][kh] = *(const short8*)(cb + off);
        blof[ms][kh] = *(const short8*)(cb + 8192 + off);
      }
    }
    float knv[2];
#pragma unroll
    for (int ms = 0; ms < 2; ++ms)
      knv[ms] = *(const float*)(cb + 16384 + (wc * 32 + ms * 16 + (lane & 15)) * 4);

    f32x4 acc[2][2];
#pragma unroll
    for (int ts = 0; ts < 2; ++ts)
#pragma unroll
      for (int ms = 0; ms < 2; ++ms) acc[ts][ms] = (f32x4){0.f, 0.f, 0.f, 0.f};
#pragma unroll
    for (int ts = 0; ts < 2; ++ts)
#pragma unroll
      for (int ms = 0; ms < 2; ++ms)
#pragma unroll
        for (int kh = 0; kh < 2; ++kh) {
          acc[ts][ms] = __builtin_amdgcn_mfma_f32_16x16x32_bf16(
              ahi[ts][kh], bhif[ms][kh], acc[ts][ms], 0, 0, 0);
          acc[ts][ms] = __builtin_amdgcn_mfma_f32_16x16x32_bf16(
              ahi[ts][kh], blof[ms][kh], acc[ts][ms], 0, 0, 0);
          acc[ts][ms] = __builtin_amdgcn_mfma_f32_16x16x32_bf16(
              alo[ts][kh], bhif[ms][kh], acc[ts][ms], 0, 0, 0);
        }
    int mg0 = mhalf * 4096 + it * 64 + wc * 32 + (lane & 15);
#pragma unroll
    for (int ts = 0; ts < 2; ++ts)
#pragma unroll
      for (int ms = 0; ms < 2; ++ms) {
        int mg = mg0 + ms * 16;
        float kv = knv[ms];
#pragma unroll
        for (int r = 0; r < 4; ++r) {
          float d2 = kv - 2.0f * acc[ts][ms][r];
          ins4(d2, mg, bd[ts][r], bi_[ts][r]);
        }
      }
    __syncthreads();
    buf ^= 1;
  }

  // ---- butterfly merge within each 16-lane group ----
#pragma unroll
  for (int st = 1; st <= 8; st <<= 1) {
#pragma unroll
    for (int ts = 0; ts < 2; ++ts)
#pragma unroll
      for (int r = 0; r < 4; ++r) {
        float sd[4]; int si[4];
#pragma unroll
        for (int s = 0; s < 4; ++s) {
          sd[s] = __shfl_xor(bd[ts][r][s], st);
          si[s] = __shfl_xor(bi_[ts][r][s], st);
        }
#pragma unroll
        for (int s = 0; s < 4; ++s) ins4(sd[s], si[s], bd[ts][r], bi_[ts][r]);
      }
  }
  float* mgd = (float*)(smem + 2 * BUFB);
  int*   mgi = (int*)(smem + 2 * BUFB + 2048);
  if ((lane & 15) == 0) {
#pragma unroll
    for (int ts = 0; ts < 2; ++ts)
#pragma unroll
      for (int r = 0; r < 4; ++r) {
        int tl = wr * 32 + ts * 16 + ((lane >> 4) << 2) + r;
#pragma unroll
        for (int s = 0; s < 4; ++s) {
          mgd[(wc * 64 + tl) * 4 + s] = bd[ts][r][s];
          mgi[(wc * 64 + tl) * 4 + s] = bi_[ts][r][s];
        }
      }
  }
  __syncthreads();
  if (tid < 64) {
    float fd[4]; int fi[4];
#pragma unroll
    for (int s = 0; s < 4; ++s) { fd[s] = mgd[tid * 4 + s]; fi[s] = mgi[tid * 4 + s]; }
#pragma unroll
    for (int s = 0; s < 4; ++s) ins4(mgd[(64 + tid) * 4 + s], mgi[(64 + tid) * 4 + s], fd, fi);
    size_t o = (((size_t)mhalf * NH + h) * TT + (t0 + tid)) * 4;
#pragma unroll
    for (int s = 0; s < 4; ++s) { pd[o + s] = fd[s]; pi[o + s] = fi[s]; }
  }
}

// ---------------- merge the two M-half partial lists ----------------
__global__ void __launch_bounds__(256) topk_merge(
    const float* __restrict__ pd, const int* __restrict__ pi, int* __restrict__ idx)
{
  int g = blockIdx.x * 256 + threadIdx.x;  // h*TT + t
  float fd[4]; int fi[4];
#pragma unroll
  for (int s = 0; s < 4; ++s) { fd[s] = pd[(size_t)g * 4 + s]; fi[s] = pi[(size_t)g * 4 + s]; }
#pragma unroll
  for (int s = 0; s < 4; ++s)
    ins4(pd[(size_t)(NH * TT + g) * 4 + s], pi[(size_t)(NH * TT + g) * 4 + s], fd, fi);
#pragma unroll
  for (int s = 0; s < 4; ++s) idx[(size_t)g * 4 + s] = fi[s];
}

// ---------------- kNN attend: one wave per (h,t) ----------------
__global__ void __launch_bounds__(256) knn_attend(
    const float* __restrict__ qkv, const float* __restrict__ att,
    const int* __restrict__ idx, const float* __restrict__ kstore,
    const float* __restrict__ vstore, float* __restrict__ vnew)
{
  int gw = (blockIdx.x * 256 + threadIdx.x) >> 6;
  int lane = threadIdx.x & 63;
  int h = gw >> 10, t = gw & 1023;
  const float* base = qkv + (size_t)t * (3 * CC) + h * DD;
  float q = base[lane];
  float k = base[CC + lane];
  float v = base[2 * CC + lane];
  float attlast = att[((size_t)h << 20) + (1023u << 10) + t];
  bool sel = attlast >= (1.0f / 8192.0f);
  const int* ix = idx + ((size_t)h * TT + t) * 4;

  float attf[5], vf[5];
  attf[0] = wredsum(q * k) * 0.125f;
  vf[0] = v;
#pragma unroll
  for (int s = 1; s < 5; ++s) {
    int m = ix[s - 1];
    const float* kp = kstore + ((size_t)h * MM + m) * DD;
    const float* vp = vstore + ((size_t)h * MM + m) * DD;
    attf[s] = wredsum(q * kp[lane]) * 0.125f;
    vf[s] = vp[lane];
  }
  float mx = attf[0];
#pragma unroll
  for (int s = 1; s < 5; ++s) mx = fmaxf(mx, attf[s]);
  float wgt[5], sum = 0.f;
#pragma unroll
  for (int s = 0; s < 5; ++s) { wgt[s] = __expf(attf[s] - mx); sum += wgt[s]; }
  float inv = 1.0f / sum;
  float vals = 0.f;
#pragma unroll
  for (int s = 0; s < 5; ++s) vals = fmaf(wgt[s] * inv, vf[s], vals);
  float r = 0.5f * vals + 0.5f * v;
  vnew[(size_t)h * TT * DD + (size_t)t * DD + lane] = sel ? r : v;
}

// ---------------- y[t, h*64+c] = sum_j att[h,t,j] * vnew[h,j,c] ----------------
__global__ void __launch_bounds__(256) gemm_att_v(
    const float* __restrict__ att, const float* __restrict__ vnew,
    float* __restrict__ y)
{
  int h = blockIdx.y;
  int m0 = blockIdx.x * 64;
  const float* A  = att + ((size_t)h << 20);
  const float* Bv = vnew + ((size_t)h << 16);
  float* Cp = y + h * DD;
  int tid = threadIdx.x, tx = tid & 15, ty = tid >> 4;
  __shared__ float As[64][17], Bs[16][65];
  float acc[4][4] = {};
  for (int k0 = 0; k0 < TT; k0 += 16) {
    __syncthreads();
    for (int i = tid; i < 1024; i += 256) {
      int r = i >> 4, c = i & 15;
      As[r][c] = A[(size_t)(m0 + r) * TT + k0 + c];
    }
    for (int i = tid; i < 1024; i += 256) {
      int r = i >> 6, c = i & 63;
      Bs[r][c] = Bv[(size_t)(k0 + r) * DD + c];
    }
    __syncthreads();
#pragma unroll
    for (int kk = 0; kk < 16; ++kk) {
      float a[4], b[4];
#pragma unroll
      for (int i = 0; i < 4; ++i) a[i] = As[ty * 4 + i][kk];
#pragma unroll
      for (int j = 0; j < 4; ++j) b[j] = Bs[kk][tx * 4 + j];
#pragma unroll
      for (int i = 0; i < 4; ++i)
#pragma unroll
        for (int j = 0; j < 4; ++j) acc[i][j] = fmaf(a[i], b[j], acc[i][j]);
    }
  }
#pragma unroll
  for (int i = 0; i < 4; ++i)
#pragma unroll
    for (int j = 0; j < 4; ++j)
      Cp[(size_t)(m0 + ty * 4 + i) * CC + tx * 4 + j] = acc[i][j];
}

// ---------------- launch ----------------
extern "C" void kernel_launch(void* const* d_in, const int* in_sizes, int n_in,
                              void* d_out, int out_size, void* d_ws, size_t ws_size,
                              hipStream_t stream) {
  (void)in_sizes; (void)n_in; (void)out_size; (void)ws_size;
  const float* x  = (const float*)d_in[0];
  const float* Wa = (const float*)d_in[1];
  const float* ba = (const float*)d_in[2];
  const float* Wp = (const float*)d_in[3];
  const float* bp = (const float*)d_in[4];
  const float* Ks = (const float*)d_in[5];
  const float* Vs = (const float*)d_in[6];
  float* out = (float*)d_out;

  float* qkv   = (float*)d_ws;                       // 1024*3072 f32
  float* att   = qkv + (size_t)TT * 3 * CC;          // 16*1024*1024 f32
  // khi/klo overlay the att region (att written only after topk)
  char*  khi   = (char*)att;                         // 16 MB
  char*  klo   = khi + (size_t)NH * MM * 128;        // 16 MB
  float* vnew  = att + (size_t)NH * TT * TT;
  float* y     = vnew + (size_t)NH * TT * DD;
  float* knorm = y + (size_t)TT * CC;
  int*   idx   = (int*)(knorm + (size_t)NH * MM);
  float* pd    = (float*)(idx + (size_t)NH * TT * 4);   // 2*16*1024*4 f32
  int*   pi    = (int*)(pd + (size_t)2 * NH * TT * 4);  // 2*16*1024*4 int

  // 1) K_store -> swizzled bf16 hi/lo + norms
  hipLaunchKernelGGL(convert_kernel, dim3(NH * MM / 256), dim3(256), 0, stream,
                     Ks, khi, klo, knorm);
  // 2) qkv = x @ Wa^T + ba
  hipLaunchKernelGGL(gemm_abt, dim3(3 * CC / 64, TT / 64, 1), dim3(256), 0, stream,
                     x, Wa, qkv, ba, CC, CC, CC, 3 * CC, 0LL, 0LL, 0LL, 1.0f);
  // 3) MFMA split-bf16 distances + partial top-4 (M split in 2)
  hipLaunchKernelGGL(topk_mfma, dim3(512), dim3(256), 0, stream,
                     qkv, khi, klo, knorm, pd, pi);
  // 4) merge partials
  hipLaunchKernelGGL(topk_merge, dim3(NH * TT / 256), dim3(256), 0, stream, pd, pi, idx);
  // 5) logits per head: att[h] = (q_h @ k_h^T) / 8
  hipLaunchKernelGGL(gemm_abt, dim3(TT / 64, TT / 64, NH), dim3(256), 0, stream,
                     qkv, qkv + CC, att, (const float*)nullptr,
                     DD, 3 * CC, 3 * CC, TT, 64LL, 64LL, (long long)TT * TT, 0.125f);
  // 6) causal softmax in place
  hipLaunchKernelGGL(softmax_causal, dim3(NH * TT / 4), dim3(256), 0, stream, att);
  // 7) kNN attention over {self} U top-4, blend, select
  hipLaunchKernelGGL(knn_attend, dim3(NH * TT / 4), dim3(256), 0, stream,
                     qkv, att, idx, Ks, Vs, vnew);
  // 8) y = att @ v_new
  hipLaunchKernelGGL(gemm_att_v, dim3(TT / 64, NH), dim3(256), 0, stream,
                     att, vnew, y);
  // 9) out = y @ Wp^T + bp
  hipLaunchKernelGGL(gemm_abt, dim3(CC / 64, TT / 64, 1), dim3(256), 0, stream,
                     y, Wp, out, bp, CC, CC, CC, CC, 0LL, 0LL, 0LL, 1.0f);
}

// Round 3
// 667.170 us; speedup vs baseline: 1.4569x; 1.2701x over previous
//
#include <hip/hip_runtime.h>
#include <math.h>

#define NH 16
#define TT 1024
#define CC 1024
#define DD 64
#define MM 8192
#define MQ 4  // M quarters
#define MQS (MM / MQ)

typedef __attribute__((ext_vector_type(8))) short short8;
typedef __attribute__((ext_vector_type(4))) float f32x4;

// ---------------- helpers ----------------
__device__ __forceinline__ float wredsum(float x) {
#pragma unroll
  for (int o = 32; o; o >>= 1) x += __shfl_xor(x, o);
  return x;
}
__device__ __forceinline__ float wredmax(float x) {
#pragma unroll
  for (int o = 32; o; o >>= 1) x = fmaxf(x, __shfl_xor(x, o));
  return x;
}

__device__ __forceinline__ unsigned int bf16rn(float x) {
  unsigned int u = __float_as_uint(x);
  return (u + 0x7fffu + ((u >> 16) & 1u)) >> 16;
}
__device__ __forceinline__ float bf16f(unsigned int h) {
  return __uint_as_float(h << 16);
}

// lexicographic (d,i) insert into ascending sorted top-4 (used in merges)
__device__ __forceinline__ void ins4(float d, int i, float vd[4], int vi[4]) {
  if (d < vd[3] || (d == vd[3] && i < vi[3])) {
    vd[3] = d; vi[3] = i;
#pragma unroll
    for (int s = 3; s > 0; --s) {
      bool sw = (vd[s] < vd[s - 1]) || (vd[s] == vd[s - 1] && vi[s] < vi[s - 1]);
      if (sw) {
        float td = vd[s]; vd[s] = vd[s - 1]; vd[s - 1] = td;
        int ti = vi[s]; vi[s] = vi[s - 1]; vi[s - 1] = ti;
      }
    }
  }
}

// strict insert: caller guarantees d < vd[3]; equal values keep earlier entry first
__device__ __forceinline__ void ins4s(float d, int i, float vd[4], int vi[4]) {
  vd[3] = d; vi[3] = i;
#pragma unroll
  for (int s = 3; s > 0; --s) {
    bool sw = vd[s] < vd[s - 1];
    if (sw) {
      float td = vd[s]; vd[s] = vd[s - 1]; vd[s - 1] = td;
      int ti = vi[s]; vi[s] = vi[s - 1]; vi[s - 1] = ti;
    }
  }
}

// ---------------- generic C = scale*(A@B^T) + bias ----------------
__global__ void __launch_bounds__(256) gemm_abt(
    const float* __restrict__ A, const float* __restrict__ B,
    float* __restrict__ Cp, const float* __restrict__ bias,
    int K, int lda, int ldb, int ldc,
    long long aB, long long bB, long long cB, float scale)
{
  A  += (size_t)blockIdx.z * aB;
  B  += (size_t)blockIdx.z * bB;
  Cp += (size_t)blockIdx.z * cB;
  int m0 = blockIdx.y * 64, n0 = blockIdx.x * 64;
  int tid = threadIdx.x, tx = tid & 15, ty = tid >> 4;
  __shared__ float As[64][17], Bs[64][17];
  float acc[4][4] = {};
  for (int k0 = 0; k0 < K; k0 += 16) {
    __syncthreads();
    for (int i = tid; i < 1024; i += 256) {
      int r = i >> 4, c = i & 15;
      As[r][c] = A[(size_t)(m0 + r) * lda + k0 + c];
      Bs[r][c] = B[(size_t)(n0 + r) * ldb + k0 + c];
    }
    __syncthreads();
#pragma unroll
    for (int kk = 0; kk < 16; ++kk) {
      float a[4], b[4];
#pragma unroll
      for (int i = 0; i < 4; ++i) a[i] = As[ty * 4 + i][kk];
#pragma unroll
      for (int j = 0; j < 4; ++j) b[j] = Bs[tx * 4 + j][kk];
#pragma unroll
      for (int i = 0; i < 4; ++i)
#pragma unroll
        for (int j = 0; j < 4; ++j) acc[i][j] = fmaf(a[i], b[j], acc[i][j]);
    }
  }
#pragma unroll
  for (int i = 0; i < 4; ++i)
#pragma unroll
    for (int j = 0; j < 4; ++j) {
      int m = m0 + ty * 4 + i, n = n0 + tx * 4 + j;
      float v = acc[i][j] * scale;
      if (bias) v += bias[n];
      Cp[(size_t)m * ldc + n] = v;
    }
}

// ---------------- causal softmax, one wave per (h, i) row ----------------
__global__ void __launch_bounds__(256) softmax_causal(float* __restrict__ att) {
  int gw = (blockIdx.x * 256 + threadIdx.x) >> 6;
  int lane = threadIdx.x & 63;
  int h = gw >> 10, i = gw & 1023;
  float* row = att + ((size_t)h << 20) + ((size_t)i << 10);
  float e[16];
  float mx = -INFINITY;
#pragma unroll
  for (int c = 0; c < 16; ++c) {
    int j = lane + (c << 6);
    float x = (j <= i) ? row[j] : -INFINITY;
    e[c] = x;
    mx = fmaxf(mx, x);
  }
  mx = wredmax(mx);
  float sum = 0.f;
#pragma unroll
  for (int c = 0; c < 16; ++c) {
    int j = lane + (c << 6);
    float v = (j <= i) ? __expf(e[c] - mx) : 0.f;
    e[c] = v;
    sum += v;
  }
  sum = wredsum(sum);
  float inv = 1.0f / sum;
#pragma unroll
  for (int c = 0; c < 16; ++c) row[lane + (c << 6)] = e[c] * inv;
}

// ---------------- convert K_store -> swizzled bf16 hi/lo + norms ----------------
// For (h,m,chunk c in 0..7): 8 bf16 stored at byte (h*MM+m)*128 + (c^(m&7))*16
__global__ void __launch_bounds__(256) convert_kernel(
    const float* __restrict__ ks, char* __restrict__ khi,
    char* __restrict__ klo, float* __restrict__ kn)
{
  int g = blockIdx.x * 256 + threadIdx.x;  // h*MM + m
  int m = g & (MM - 1);
  const float* src = ks + (size_t)g * DD;
  float nrm = 0.f;
  size_t rowb = (size_t)g * 128;
#pragma unroll
  for (int c = 0; c < 8; ++c) {
    float f[8];
#pragma unroll
    for (int j = 0; j < 8; ++j) {
      f[j] = src[c * 8 + j];
      nrm = fmaf(f[j], f[j], nrm);
    }
    uint4 hv, lv;
    unsigned int hw[4], lw[4];
#pragma unroll
    for (int p = 0; p < 4; ++p) {
      unsigned int h0 = bf16rn(f[2 * p]), h1 = bf16rn(f[2 * p + 1]);
      float r0 = f[2 * p] - bf16f(h0), r1 = f[2 * p + 1] - bf16f(h1);
      hw[p] = h0 | (h1 << 16);
      lw[p] = bf16rn(r0) | (bf16rn(r1) << 16);
    }
    hv.x = hw[0]; hv.y = hw[1]; hv.z = hw[2]; hv.w = hw[3];
    lv.x = lw[0]; lv.y = lw[1]; lv.z = lw[2]; lv.w = lw[3];
    size_t off = rowb + (size_t)(((c ^ (m & 7)) << 4));
    *(uint4*)(khi + off) = hv;
    *(uint4*)(klo + off) = lv;
  }
  kn[g] = nrm;
}

// ---------------- staging helpers (global -> LDS direct) ----------------
__device__ __forceinline__ void stage_seg16(const char* gsrc, char* ldst, int lane) {
  __builtin_amdgcn_global_load_lds(
      (const __attribute__((address_space(1))) unsigned int*)(gsrc + lane * 16),
      (__attribute__((address_space(3))) unsigned int*)ldst, 16, 0, 0);
}
__device__ __forceinline__ void stage_seg4(const char* gsrc, char* ldst, int lane) {
  __builtin_amdgcn_global_load_lds(
      (const __attribute__((address_space(1))) unsigned int*)(gsrc + lane * 4),
      (__attribute__((address_space(3))) unsigned int*)ldst, 4, 0, 0);
}

// ---------------- MFMA distance + top-4 (v2: one list per thread) ----------------
// grid 1024: bid -> h = bid&15, ttile = (bid>>4)&15, mq = bid>>8
// block = 4 waves; wave w owns 16 t-rows (t0 = ttile*64 + w*16).
// MFMA: A = K_store tile (m), B = k rows (t)  =>  C col = t (lane&15), row = m.
#define BUFB 16640  // 16384 tile (khi 8K + klo 8K) + 256 knorm
__global__ void __launch_bounds__(256, 4) topk_mfma(
    const float* __restrict__ qkv, const char* __restrict__ khi,
    const char* __restrict__ klo, const float* __restrict__ knorm,
    float* __restrict__ pd, int* __restrict__ pi)
{
  int bid = blockIdx.x;
  int h = bid & 15, ttile = (bid >> 4) & 15, mq = bid >> 8;
  int tid = threadIdx.x, lane = tid & 63, w = tid >> 6;
  int t0 = ttile * 64 + w * 16;
  __shared__ __align__(16) char smem[2 * BUFB];

  // B fragments: this wave's 16 k-rows (t = t0 + (lane&15)), hi/lo, 2 k-halves
  short8 bhi[2], blo[2];
  {
    const float* rowp = qkv + (size_t)(t0 + (lane & 15)) * (3 * CC) + CC + h * DD;
#pragma unroll
    for (int kh = 0; kh < 2; ++kh) {
      const float* p = rowp + kh * 32 + (lane >> 4) * 8;
#pragma unroll
      for (int j = 0; j < 8; ++j) {
        float a = p[j];
        unsigned int hb = bf16rn(a);
        bhi[kh][j] = (short)hb;
        blo[kh][j] = (short)bf16rn(a - bf16f(hb));
      }
    }
  }

  const char* ghi = khi + ((size_t)h * MM + (size_t)mq * MQS) * 128;
  const char* glo = klo + ((size_t)h * MM + (size_t)mq * MQS) * 128;
  const char* gkn = (const char*)(knorm + (size_t)h * MM + (size_t)mq * MQS);

  float bd[4] = {3.0e38f, 3.0e38f, 3.0e38f, 3.0e38f};
  int   bi_[4] = {-1, -1, -1, -1};

  // prologue: stage tile 0
  {
    char* nb = smem;
#pragma unroll
    for (int i2 = 0; i2 < 4; ++i2) {
      int s = w * 4 + i2;
      const char* src = (s < 8) ? (ghi + s * 1024) : (glo + (s - 8) * 1024);
      stage_seg16(src, nb + s * 1024, lane);
    }
    if (w == 0) stage_seg4(gkn, nb + 16384, lane);
  }
  __syncthreads();

  int buf = 0;
  const int NIT = MQS / 64;  // 32
  for (int it = 0; it < NIT; ++it) {
    char* cb = smem + buf * BUFB;
    if (it < NIT - 1) {  // issue next-tile stage before compute
      char* nb = smem + (buf ^ 1) * BUFB;
      const char* bh = ghi + (size_t)(it + 1) * 8192;
      const char* bl = glo + (size_t)(it + 1) * 8192;
#pragma unroll
      for (int i2 = 0; i2 < 4; ++i2) {
        int s = w * 4 + i2;
        const char* src = (s < 8) ? (bh + s * 1024) : (bl + (s - 8) * 1024);
        stage_seg16(src, nb + s * 1024, lane);
      }
      if (w == 0) stage_seg4(gkn + (size_t)(it + 1) * 256, nb + 16384, lane);
    }

    // compute: per ms-subtile load A frags and run its 6 MFMAs
    f32x4 acc[4];
#pragma unroll
    for (int ms = 0; ms < 4; ++ms) acc[ms] = (f32x4){0.f, 0.f, 0.f, 0.f};
#pragma unroll
    for (int ms = 0; ms < 4; ++ms) {
      int mloc = ms * 16 + (lane & 15);
      short8 ah[2], al[2];
#pragma unroll
      for (int kh = 0; kh < 2; ++kh) {
        int c = kh * 4 + (lane >> 4);
        int off = mloc * 128 + (((c ^ (mloc & 7)) << 4));
        ah[kh] = *(const short8*)(cb + off);
        al[kh] = *(const short8*)(cb + 8192 + off);
      }
#pragma unroll
      for (int kh = 0; kh < 2; ++kh) {
        acc[ms] = __builtin_amdgcn_mfma_f32_16x16x32_bf16(ah[kh], bhi[kh], acc[ms], 0, 0, 0);
        acc[ms] = __builtin_amdgcn_mfma_f32_16x16x32_bf16(al[kh], bhi[kh], acc[ms], 0, 0, 0);
        acc[ms] = __builtin_amdgcn_mfma_f32_16x16x32_bf16(ah[kh], blo[kh], acc[ms], 0, 0, 0);
      }
    }

    // knorm for this thread's 16 m-values
    f32x4 knv[4];
#pragma unroll
    for (int ms = 0; ms < 4; ++ms)
      knv[ms] = *(const f32x4*)(cb + 16384 + (ms * 16 + ((lane >> 4) << 2)) * 4);

    // d2 = ||K||^2 - 2 k.K
    float d2v[4][4];
#pragma unroll
    for (int ms = 0; ms < 4; ++ms)
#pragma unroll
      for (int r = 0; r < 4; ++r)
        d2v[ms][r] = fmaf(-2.0f, acc[ms][r], knv[ms][r]);

    int mg0 = mq * MQS + it * 64 + ((lane >> 4) << 2);

    float mn = 3.0e38f;
#pragma unroll
    for (int ms = 0; ms < 4; ++ms)
#pragma unroll
      for (int r = 0; r < 4; ++r) mn = fminf(mn, d2v[ms][r]);

    while (mn < bd[3]) {
      float dm = mn;
      int am = 0x7fffffff;
#pragma unroll
      for (int ms = 0; ms < 4; ++ms)
#pragma unroll
        for (int r = 0; r < 4; ++r) {
          int mgidx = mg0 + ms * 16 + r;
          int cand = (d2v[ms][r] == dm) ? mgidx : 0x7fffffff;
          am = (cand < am) ? cand : am;
        }
      ins4s(dm, am, bd, bi_);
#pragma unroll
      for (int ms = 0; ms < 4; ++ms)
#pragma unroll
        for (int r = 0; r < 4; ++r) {
          int mgidx = mg0 + ms * 16 + r;
          if (mgidx == am) d2v[ms][r] = 3.0e38f;
        }
      mn = 3.0e38f;
#pragma unroll
      for (int ms = 0; ms < 4; ++ms)
#pragma unroll
        for (int r = 0; r < 4; ++r) mn = fminf(mn, d2v[ms][r]);
    }

    __syncthreads();
    buf ^= 1;
  }

  // butterfly merge across the 4 lane-groups holding the same t (lex ties)
#pragma unroll
  for (int st = 16; st <= 32; st <<= 1) {
    float sd[4]; int si[4];
#pragma unroll
    for (int s = 0; s < 4; ++s) {
      sd[s] = __shfl_xor(bd[s], st);
      si[s] = __shfl_xor(bi_[s], st);
    }
#pragma unroll
    for (int s = 0; s < 4; ++s) ins4(sd[s], si[s], bd, bi_);
  }
  if (lane < 16) {
    size_t o = (((size_t)mq * NH + h) * TT + (t0 + lane)) * 4;
#pragma unroll
    for (int s = 0; s < 4; ++s) { pd[o + s] = bd[s]; pi[o + s] = bi_[s]; }
  }
}

// ---------------- merge the 4 M-quarter partial lists ----------------
__global__ void __launch_bounds__(256) topk_merge(
    const float* __restrict__ pd, const int* __restrict__ pi, int* __restrict__ idx)
{
  int g = blockIdx.x * 256 + threadIdx.x;  // h*TT + t
  float fd[4]; int fi[4];
#pragma unroll
  for (int s = 0; s < 4; ++s) { fd[s] = pd[(size_t)g * 4 + s]; fi[s] = pi[(size_t)g * 4 + s]; }
#pragma unroll
  for (int q = 1; q < MQ; ++q)
#pragma unroll
    for (int s = 0; s < 4; ++s)
      ins4(pd[(size_t)(q * NH * TT + g) * 4 + s], pi[(size_t)(q * NH * TT + g) * 4 + s], fd, fi);
#pragma unroll
  for (int s = 0; s < 4; ++s) idx[(size_t)g * 4 + s] = fi[s];
}

// ---------------- kNN attend: one wave per (h,t) ----------------
__global__ void __launch_bounds__(256) knn_attend(
    const float* __restrict__ qkv, const float* __restrict__ att,
    const int* __restrict__ idx, const float* __restrict__ kstore,
    const float* __restrict__ vstore, float* __restrict__ vnew)
{
  int gw = (blockIdx.x * 256 + threadIdx.x) >> 6;
  int lane = threadIdx.x & 63;
  int h = gw >> 10, t = gw & 1023;
  const float* base = qkv + (size_t)t * (3 * CC) + h * DD;
  float q = base[lane];
  float k = base[CC + lane];
  float v = base[2 * CC + lane];
  float attlast = att[((size_t)h << 20) + (1023u << 10) + t];
  bool sel = attlast >= (1.0f / 8192.0f);
  const int* ix = idx + ((size_t)h * TT + t) * 4;

  float attf[5], vf[5];
  attf[0] = wredsum(q * k) * 0.125f;
  vf[0] = v;
#pragma unroll
  for (int s = 1; s < 5; ++s) {
    int m = ix[s - 1];
    const float* kp = kstore + ((size_t)h * MM + m) * DD;
    const float* vp = vstore + ((size_t)h * MM + m) * DD;
    attf[s] = wredsum(q * kp[lane]) * 0.125f;
    vf[s] = vp[lane];
  }
  float mx = attf[0];
#pragma unroll
  for (int s = 1; s < 5; ++s) mx = fmaxf(mx, attf[s]);
  float wgt[5], sum = 0.f;
#pragma unroll
  for (int s = 0; s < 5; ++s) { wgt[s] = __expf(attf[s] - mx); sum += wgt[s]; }
  float inv = 1.0f / sum;
  float vals = 0.f;
#pragma unroll
  for (int s = 0; s < 5; ++s) vals = fmaf(wgt[s] * inv, vf[s], vals);
  float r = 0.5f * vals + 0.5f * v;
  vnew[(size_t)h * TT * DD + (size_t)t * DD + lane] = sel ? r : v;
}

// ---------------- y[t, h*64+c] = sum_j att[h,t,j] * vnew[h,j,c] ----------------
__global__ void __launch_bounds__(256) gemm_att_v(
    const float* __restrict__ att, const float* __restrict__ vnew,
    float* __restrict__ y)
{
  int h = blockIdx.y;
  int m0 = blockIdx.x * 64;
  const float* A  = att + ((size_t)h << 20);
  const float* Bv = vnew + ((size_t)h << 16);
  float* Cp = y + h * DD;
  int tid = threadIdx.x, tx = tid & 15, ty = tid >> 4;
  __shared__ float As[64][17], Bs[16][65];
  float acc[4][4] = {};
  for (int k0 = 0; k0 < TT; k0 += 16) {
    __syncthreads();
    for (int i = tid; i < 1024; i += 256) {
      int r = i >> 4, c = i & 15;
      As[r][c] = A[(size_t)(m0 + r) * TT + k0 + c];
    }
    for (int i = tid; i < 1024; i += 256) {
      int r = i >> 6, c = i & 63;
      Bs[r][c] = Bv[(size_t)(k0 + r) * DD + c];
    }
    __syncthreads();
#pragma unroll
    for (int kk = 0; kk < 16; ++kk) {
      float a[4], b[4];
#pragma unroll
      for (int i = 0; i < 4; ++i) a[i] = As[ty * 4 + i][kk];
#pragma unroll
      for (int j = 0; j < 4; ++j) b[j] = Bs[kk][tx * 4 + j];
#pragma unroll
      for (int i = 0; i < 4; ++i)
#pragma unroll
        for (int j = 0; j < 4; ++j) acc[i][j] = fmaf(a[i], b[j], acc[i][j]);
    }
  }
#pragma unroll
  for (int i = 0; i < 4; ++i)
#pragma unroll
    for (int j = 0; j < 4; ++j)
      Cp[(size_t)(m0 + ty * 4 + i) * CC + tx * 4 + j] = acc[i][j];
}

// ---------------- launch ----------------
extern "C" void kernel_launch(void* const* d_in, const int* in_sizes, int n_in,
                              void* d_out, int out_size, void* d_ws, size_t ws_size,
                              hipStream_t stream) {
  (void)in_sizes; (void)n_in; (void)out_size; (void)ws_size;
  const float* x  = (const float*)d_in[0];
  const float* Wa = (const float*)d_in[1];
  const float* ba = (const float*)d_in[2];
  const float* Wp = (const float*)d_in[3];
  const float* bp = (const float*)d_in[4];
  const float* Ks = (const float*)d_in[5];
  const float* Vs = (const float*)d_in[6];
  float* out = (float*)d_out;

  float* qkv   = (float*)d_ws;                       // 1024*3072 f32
  float* att   = qkv + (size_t)TT * 3 * CC;          // 16*1024*1024 f32
  // khi/klo overlay the att region (att written only after topk)
  char*  khi   = (char*)att;                         // 16 MB
  char*  klo   = khi + (size_t)NH * MM * 128;        // 16 MB
  float* vnew  = att + (size_t)NH * TT * TT;
  float* y     = vnew + (size_t)NH * TT * DD;
  float* knorm = y + (size_t)TT * CC;
  int*   idx   = (int*)(knorm + (size_t)NH * MM);
  float* pd    = (float*)(idx + (size_t)NH * TT * 4);    // MQ*16*1024*4 f32
  int*   pi    = (int*)(pd + (size_t)MQ * NH * TT * 4);  // MQ*16*1024*4 int

  // 1) K_store -> swizzled bf16 hi/lo + norms
  hipLaunchKernelGGL(convert_kernel, dim3(NH * MM / 256), dim3(256), 0, stream,
                     Ks, khi, klo, knorm);
  // 2) qkv = x @ Wa^T + ba
  hipLaunchKernelGGL(gemm_abt, dim3(3 * CC / 64, TT / 64, 1), dim3(256), 0, stream,
                     x, Wa, qkv, ba, CC, CC, CC, 3 * CC, 0LL, 0LL, 0LL, 1.0f);
  // 3) MFMA split-bf16 distances + partial top-4 (M split in 4)
  hipLaunchKernelGGL(topk_mfma, dim3(16 * 16 * MQ), dim3(256), 0, stream,
                     qkv, khi, klo, knorm, pd, pi);
  // 4) merge partials
  hipLaunchKernelGGL(topk_merge, dim3(NH * TT / 256), dim3(256), 0, stream, pd, pi, idx);
  // 5) logits per head: att[h] = (q_h @ k_h^T) / 8
  hipLaunchKernelGGL(gemm_abt, dim3(TT / 64, TT / 64, NH), dim3(256), 0, stream,
                     qkv, qkv + CC, att, (const float*)nullptr,
                     DD, 3 * CC, 3 * CC, TT, 64LL, 64LL, (long long)TT * TT, 0.125f);
  // 6) causal softmax in place
  hipLaunchKernelGGL(softmax_causal, dim3(NH * TT / 4), dim3(256), 0, stream, att);
  // 7) kNN attention over {self} U top-4, blend, select
  hipLaunchKernelGGL(knn_attend, dim3(NH * TT / 4), dim3(256), 0, stream,
                     qkv, att, idx, Ks, Vs, vnew);
  // 8) y = att @ v_new
  hipLaunchKernelGGL(gemm_att_v, dim3(TT / 64, NH), dim3(256), 0, stream,
                     att, vnew, y);
  // 9) out = y @ Wp^T + bp
  hipLaunchKernelGGL(gemm_abt, dim3(CC / 64, TT / 64, 1), dim3(256), 0, stream,
                     y, Wp, out, bp, CC, CC, CC, CC, 0LL, 0LL, 0LL, 1.0f);
}

// Round 4
// 281.814 us; speedup vs baseline: 3.4491x; 2.3674x over previous
//
#include <hip/hip_runtime.h>
#include <math.h>

#define NH 16
#define TT 1024
#define CC 1024
#define DD 64
#define MM 8192
#define MQ 4
#define MQS (MM / MQ)

typedef __attribute__((ext_vector_type(8))) short short8;
typedef __attribute__((ext_vector_type(4))) float f32x4;

// ---------------- helpers ----------------
__device__ __forceinline__ float wredsum(float x) {
#pragma unroll
  for (int o = 32; o; o >>= 1) x += __shfl_xor(x, o);
  return x;
}
__device__ __forceinline__ float wredmax(float x) {
#pragma unroll
  for (int o = 32; o; o >>= 1) x = fmaxf(x, __shfl_xor(x, o));
  return x;
}
__device__ __forceinline__ unsigned int bf16rn(float x) {
  unsigned int u = __float_as_uint(x);
  return (u + 0x7fffu + ((u >> 16) & 1u)) >> 16;
}
__device__ __forceinline__ float bf16f(unsigned int h) {
  return __uint_as_float(h << 16);
}
// HL layout: element (r,k) of [R][K] matrix; 16B chunks swizzled by r&7 in each 64-elem block
__device__ __forceinline__ size_t hl_off(int r, int k, int K) {
  return (size_t)(r * K + (k & ~63)) * 2 + ((((k >> 3) & 7) ^ (r & 7)) << 4) + ((k & 7) << 1);
}

__device__ __forceinline__ void ins4(float d, int i, float vd[4], int vi[4]) {
  if (d < vd[3] || (d == vd[3] && i < vi[3])) {
    vd[3] = d; vi[3] = i;
#pragma unroll
    for (int s = 3; s > 0; --s) {
      bool sw = (vd[s] < vd[s - 1]) || (vd[s] == vd[s - 1] && vi[s] < vi[s - 1]);
      if (sw) {
        float td = vd[s]; vd[s] = vd[s - 1]; vd[s - 1] = td;
        int ti = vi[s]; vi[s] = vi[s - 1]; vi[s - 1] = ti;
      }
    }
  }
}
__device__ __forceinline__ void ins4s(float d, int i, float vd[4], int vi[4]) {
  vd[3] = d; vi[3] = i;
#pragma unroll
  for (int s = 3; s > 0; --s) {
    bool sw = vd[s] < vd[s - 1];
    if (sw) {
      float td = vd[s]; vd[s] = vd[s - 1]; vd[s - 1] = td;
      int ti = vi[s]; vi[s] = vi[s - 1]; vi[s - 1] = ti;
    }
  }
}

// ---------------- staging (global -> LDS direct) ----------------
__device__ __forceinline__ void stage_seg16(const char* gsrc, char* ldst, int lane) {
  __builtin_amdgcn_global_load_lds(
      (const __attribute__((address_space(1))) unsigned int*)(gsrc + lane * 16),
      (__attribute__((address_space(3))) unsigned int*)ldst, 16, 0, 0);
}
__device__ __forceinline__ void stage_seg4(const char* gsrc, char* ldst, int lane) {
  __builtin_amdgcn_global_load_lds(
      (const __attribute__((address_space(1))) unsigned int*)(gsrc + lane * 4),
      (__attribute__((address_space(3))) unsigned int*)ldst, 4, 0, 0);
}
// stage 8 rows x 128B (one wave-call); per-lane global addr, linear LDS dest
__device__ __forceinline__ void stage_rows8(const char* gRow0, size_t gStride, char* lds, int lane) {
  __builtin_amdgcn_global_load_lds(
      (const __attribute__((address_space(1))) unsigned int*)(gRow0 + (size_t)(lane >> 3) * gStride + ((lane & 7) << 4)),
      (__attribute__((address_space(3))) unsigned int*)lds, 16, 0, 0);
}

// ---------------- convert f32 [R][1024] -> HL ----------------
__global__ void __launch_bounds__(256) convert_hl(
    const float* __restrict__ src, char* __restrict__ hi, char* __restrict__ lo, int nChunks)
{
  int gc = blockIdx.x * 256 + threadIdx.x;  // one 8-elem chunk
  if (gc >= nChunks) return;
  int r = gc >> 7, c = gc & 127;  // K=1024: 128 chunks/row
  const float* p = src + ((size_t)r << 10) + (c << 3);
  float4 f0 = *(const float4*)p;
  float4 f1 = *(const float4*)(p + 4);
  float f[8] = {f0.x, f0.y, f0.z, f0.w, f1.x, f1.y, f1.z, f1.w};
  short8 hv, lv;
#pragma unroll
  for (int e = 0; e < 8; ++e) {
    unsigned hb = bf16rn(f[e]);
    hv[e] = (short)hb;
    lv[e] = (short)bf16rn(f[e] - bf16f(hb));
  }
  size_t off = ((size_t)(r << 10) + ((c & ~7) << 3)) * 2 + (((c & 7) ^ (r & 7)) << 4);
  *(short8*)(hi + off) = hv;
  *(short8*)(lo + off) = lv;
}

// ---------------- K_store -> HL(K=64) + norms ----------------
__global__ void __launch_bounds__(256) convert_kernel(
    const float* __restrict__ ks, char* __restrict__ khi,
    char* __restrict__ klo, float* __restrict__ kn)
{
  int g = blockIdx.x * 256 + threadIdx.x;  // h*MM + m
  int m = g & (MM - 1);
  const float* src = ks + (size_t)g * DD;
  float nrm = 0.f;
  size_t rowb = (size_t)g * 128;
#pragma unroll
  for (int c = 0; c < 8; ++c) {
    float f[8];
#pragma unroll
    for (int j = 0; j < 8; ++j) {
      f[j] = src[c * 8 + j];
      nrm = fmaf(f[j], f[j], nrm);
    }
    uint4 hv, lv;
    unsigned int hw[4], lw[4];
#pragma unroll
    for (int p = 0; p < 4; ++p) {
      unsigned int h0 = bf16rn(f[2 * p]), h1 = bf16rn(f[2 * p + 1]);
      float r0 = f[2 * p] - bf16f(h0), r1 = f[2 * p + 1] - bf16f(h1);
      hw[p] = h0 | (h1 << 16);
      lw[p] = bf16rn(r0) | (bf16rn(r1) << 16);
    }
    hv.x = hw[0]; hv.y = hw[1]; hv.z = hw[2]; hv.w = hw[3];
    lv.x = lw[0]; lv.y = lw[1]; lv.z = lw[2]; lv.w = lw[3];
    size_t off = rowb + (size_t)(((c ^ (m & 7)) << 4));
    *(uint4*)(khi + off) = hv;
    *(uint4*)(klo + off) = lv;
  }
  kn[g] = nrm;
}

// ---------------- generic split-bf16 MFMA GEMM: C = scale*(A@B^T)+bias ----------------
// A,B in HL layout. 128x128 tile, BK=64, 4 waves (2x2), wave tile 64x64.
__global__ void __launch_bounds__(256) gemm_hl(
    const char* __restrict__ Ahi, const char* __restrict__ Alo, int strideA, int aKb0, int aKbz,
    const char* __restrict__ Bhi, const char* __restrict__ Blo, int strideB, int bKb0, int bKbz,
    int kbBeg, int kbCnt, int kbzStep,
    float* __restrict__ Cf, long long czMul, int ldc,
    char* __restrict__ Chi, char* __restrict__ Clo, int Kc,
    const float* __restrict__ bias, float scale, int causal)
{
  int bx = blockIdx.x, by = blockIdx.y, z = blockIdx.z;
  int n0 = bx * 128, m0 = by * 128;
  if (causal && n0 > m0 + 127) return;
  int tid = threadIdx.x, lane = tid & 63, w = tid >> 6;
  int wr = w >> 1, wc = w & 1;
  __shared__ __align__(16) char smem[65536];
  char* sAhi = smem;
  char* sAlo = smem + 16384;
  char* sBhi = smem + 32768;
  char* sBlo = smem + 49152;
  f32x4 acc[4][4];
#pragma unroll
  for (int i = 0; i < 4; ++i)
#pragma unroll
    for (int j = 0; j < 4; ++j) acc[i][j] = (f32x4){0.f, 0.f, 0.f, 0.f};

  int kb0 = kbBeg + z * kbzStep;
  int lr = lane & 15, lc = lane >> 4;
  for (int i = 0; i < kbCnt; ++i) {
    int kbA = aKb0 + z * aKbz + kb0 + i;
    int kbB = bKb0 + z * bKbz + kb0 + i;
    if (i) __syncthreads();
#pragma unroll
    for (int c8 = 0; c8 < 4; ++c8) {
      int r8 = w * 32 + c8 * 8;
      stage_rows8(Ahi + (size_t)(m0 + r8) * strideA + (size_t)kbA * 128, strideA, sAhi + r8 * 128, lane);
      stage_rows8(Alo + (size_t)(m0 + r8) * strideA + (size_t)kbA * 128, strideA, sAlo + r8 * 128, lane);
      stage_rows8(Bhi + (size_t)(n0 + r8) * strideB + (size_t)kbB * 128, strideB, sBhi + r8 * 128, lane);
      stage_rows8(Blo + (size_t)(n0 + r8) * strideB + (size_t)kbB * 128, strideB, sBlo + r8 * 128, lane);
    }
    __syncthreads();
#pragma unroll
    for (int kh = 0; kh < 2; ++kh) {
      short8 ah[4], al[4], bh[4], bl[4];
#pragma unroll
      for (int f = 0; f < 4; ++f) {
        int ra = wr * 64 + f * 16 + lr;
        int ca = ((kh * 4 + lc) ^ (ra & 7)) << 4;
        ah[f] = *(const short8*)(sAhi + ra * 128 + ca);
        al[f] = *(const short8*)(sAlo + ra * 128 + ca);
        int rb = wc * 64 + f * 16 + lr;
        int cb = ((kh * 4 + lc) ^ (rb & 7)) << 4;
        bh[f] = *(const short8*)(sBhi + rb * 128 + cb);
        bl[f] = *(const short8*)(sBlo + rb * 128 + cb);
      }
#pragma unroll
      for (int mi = 0; mi < 4; ++mi)
#pragma unroll
        for (int nj = 0; nj < 4; ++nj) {
          acc[mi][nj] = __builtin_amdgcn_mfma_f32_16x16x32_bf16(ah[mi], bh[nj], acc[mi][nj], 0, 0, 0);
          acc[mi][nj] = __builtin_amdgcn_mfma_f32_16x16x32_bf16(al[mi], bh[nj], acc[mi][nj], 0, 0, 0);
          acc[mi][nj] = __builtin_amdgcn_mfma_f32_16x16x32_bf16(ah[mi], bl[nj], acc[mi][nj], 0, 0, 0);
        }
    }
  }
#pragma unroll
  for (int mi = 0; mi < 4; ++mi)
#pragma unroll
    for (int nj = 0; nj < 4; ++nj)
#pragma unroll
      for (int r = 0; r < 4; ++r) {
        int m = m0 + wr * 64 + mi * 16 + lc * 4 + r;
        int n = n0 + wc * 64 + nj * 16 + lr;
        float v = acc[mi][nj][r] * scale;
        if (bias) v += bias[n];
        if (Cf) Cf[(size_t)z * czMul + (size_t)m * ldc + n] = v;
        if (Chi) {
          unsigned hb = bf16rn(v);
          *(unsigned short*)(Chi + hl_off(m, n, Kc)) = (unsigned short)hb;
          *(unsigned short*)(Clo + hl_off(m, n, Kc)) = (unsigned short)bf16rn(v - bf16f(hb));
        }
      }
}

// ---------------- causal softmax; writes HL in place + f32 last row ----------------
__global__ void __launch_bounds__(256) softmax_causal(float* __restrict__ att,
                                                      float* __restrict__ attlast) {
  int gw = (blockIdx.x * 256 + threadIdx.x) >> 6;
  int lane = threadIdx.x & 63;
  int h = gw >> 10, i = gw & 1023;
  float* row = att + ((size_t)h << 20) + ((size_t)i << 10);
  float e[16];
  float mx = -INFINITY;
#pragma unroll
  for (int c = 0; c < 16; ++c) {
    int j = lane + (c << 6);
    float xx = (j <= i) ? row[j] : -INFINITY;
    e[c] = xx;
    mx = fmaxf(mx, xx);
  }
  mx = wredmax(mx);
  float sum = 0.f;
#pragma unroll
  for (int c = 0; c < 16; ++c) {
    int j = lane + (c << 6);
    float v = (j <= i) ? __expf(e[c] - mx) : 0.f;
    e[c] = v;
    sum += v;
  }
  sum = wredsum(sum);
  float inv = 1.0f / sum;
  char* rowb = (char*)row;
  int sw = ((lane >> 3) ^ (i & 7)) << 4;
  int o2 = (lane & 7) << 1;
#pragma unroll
  for (int c = 0; c < 16; ++c) {
    float v = e[c] * inv;
    unsigned hb = bf16rn(v);
    unsigned lb = bf16rn(v - bf16f(hb));
    *(unsigned short*)(rowb + c * 128 + sw + o2) = (unsigned short)hb;
    *(unsigned short*)(rowb + 2048 + c * 128 + sw + o2) = (unsigned short)lb;
    if (i == 1023) attlast[(h << 10) + lane + (c << 6)] = v;
  }
}

// ---------------- MFMA distance + top-4 ----------------
#define BUFB 16640
__global__ void __launch_bounds__(256, 4) topk_mfma(
    const char* __restrict__ qhi, const char* __restrict__ qlo,
    const char* __restrict__ khi, const char* __restrict__ klo,
    const float* __restrict__ knorm, float* __restrict__ pd, int* __restrict__ pi)
{
  int bid = blockIdx.x;
  int h = bid & 15, ttile = (bid >> 4) & 15, mq = bid >> 8;
  int tid = threadIdx.x, lane = tid & 63, w = tid >> 6;
  int t0 = ttile * 64 + w * 16;
  __shared__ __align__(16) char smem[2 * BUFB];

  // B fragments: k rows from qkvhl (cols 1024 + h*64 ..)
  short8 bhi[2], blo[2];
  {
    int t = t0 + (lane & 15);
    size_t rb = (size_t)t * 6144 + 2048 + h * 128;
#pragma unroll
    for (int kh = 0; kh < 2; ++kh) {
      int chunk = kh * 4 + (lane >> 4);
      size_t off = rb + ((chunk ^ (t & 7)) << 4);
      bhi[kh] = *(const short8*)(qhi + off);
      blo[kh] = *(const short8*)(qlo + off);
    }
  }

  const char* ghi = khi + ((size_t)h * MM + (size_t)mq * MQS) * 128;
  const char* glo = klo + ((size_t)h * MM + (size_t)mq * MQS) * 128;
  const char* gkn = (const char*)(knorm + (size_t)h * MM + (size_t)mq * MQS);

  float bd[4] = {3.0e38f, 3.0e38f, 3.0e38f, 3.0e38f};
  int   bi_[4] = {-1, -1, -1, -1};

  {
    char* nb = smem;
#pragma unroll
    for (int i2 = 0; i2 < 4; ++i2) {
      int s = w * 4 + i2;
      const char* src = (s < 8) ? (ghi + s * 1024) : (glo + (s - 8) * 1024);
      stage_seg16(src, nb + s * 1024, lane);
    }
    if (w == 0) stage_seg4(gkn, nb + 16384, lane);
  }
  __syncthreads();

  int buf = 0;
  const int NIT = MQS / 64;
  for (int it = 0; it < NIT; ++it) {
    char* cb = smem + buf * BUFB;
    if (it < NIT - 1) {
      char* nb = smem + (buf ^ 1) * BUFB;
      const char* bh = ghi + (size_t)(it + 1) * 8192;
      const char* bl = glo + (size_t)(it + 1) * 8192;
#pragma unroll
      for (int i2 = 0; i2 < 4; ++i2) {
        int s = w * 4 + i2;
        const char* src = (s < 8) ? (bh + s * 1024) : (bl + (s - 8) * 1024);
        stage_seg16(src, nb + s * 1024, lane);
      }
      if (w == 0) stage_seg4(gkn + (size_t)(it + 1) * 256, nb + 16384, lane);
    }

    f32x4 acc[4];
#pragma unroll
    for (int ms = 0; ms < 4; ++ms) acc[ms] = (f32x4){0.f, 0.f, 0.f, 0.f};
#pragma unroll
    for (int ms = 0; ms < 4; ++ms) {
      int mloc = ms * 16 + (lane & 15);
      short8 ah[2], al[2];
#pragma unroll
      for (int kh = 0; kh < 2; ++kh) {
        int c = kh * 4 + (lane >> 4);
        int off = mloc * 128 + (((c ^ (mloc & 7)) << 4));
        ah[kh] = *(const short8*)(cb + off);
        al[kh] = *(const short8*)(cb + 8192 + off);
      }
#pragma unroll
      for (int kh = 0; kh < 2; ++kh) {
        acc[ms] = __builtin_amdgcn_mfma_f32_16x16x32_bf16(ah[kh], bhi[kh], acc[ms], 0, 0, 0);
        acc[ms] = __builtin_amdgcn_mfma_f32_16x16x32_bf16(al[kh], bhi[kh], acc[ms], 0, 0, 0);
        acc[ms] = __builtin_amdgcn_mfma_f32_16x16x32_bf16(ah[kh], blo[kh], acc[ms], 0, 0, 0);
      }
    }

    f32x4 knv[4];
#pragma unroll
    for (int ms = 0; ms < 4; ++ms)
      knv[ms] = *(const f32x4*)(cb + 16384 + (ms * 16 + ((lane >> 4) << 2)) * 4);

    float d2v[4][4];
#pragma unroll
    for (int ms = 0; ms < 4; ++ms)
#pragma unroll
      for (int r = 0; r < 4; ++r)
        d2v[ms][r] = fmaf(-2.0f, acc[ms][r], knv[ms][r]);

    int mg0 = mq * MQS + it * 64 + ((lane >> 4) << 2);

    float mn = 3.0e38f;
#pragma unroll
    for (int ms = 0; ms < 4; ++ms)
#pragma unroll
      for (int r = 0; r < 4; ++r) mn = fminf(mn, d2v[ms][r]);

    while (mn < bd[3]) {
      float dm = mn;
      int am = 0x7fffffff;
#pragma unroll
      for (int ms = 0; ms < 4; ++ms)
#pragma unroll
        for (int r = 0; r < 4; ++r) {
          int mgidx = mg0 + ms * 16 + r;
          int cand = (d2v[ms][r] == dm) ? mgidx : 0x7fffffff;
          am = (cand < am) ? cand : am;
        }
      ins4s(dm, am, bd, bi_);
#pragma unroll
      for (int ms = 0; ms < 4; ++ms)
#pragma unroll
        for (int r = 0; r < 4; ++r) {
          int mgidx = mg0 + ms * 16 + r;
          if (mgidx == am) d2v[ms][r] = 3.0e38f;
        }
      mn = 3.0e38f;
#pragma unroll
      for (int ms = 0; ms < 4; ++ms)
#pragma unroll
        for (int r = 0; r < 4; ++r) mn = fminf(mn, d2v[ms][r]);
    }

    __syncthreads();
    buf ^= 1;
  }

#pragma unroll
  for (int st = 16; st <= 32; st <<= 1) {
    float sd[4]; int si[4];
#pragma unroll
    for (int s = 0; s < 4; ++s) {
      sd[s] = __shfl_xor(bd[s], st);
      si[s] = __shfl_xor(bi_[s], st);
    }
#pragma unroll
    for (int s = 0; s < 4; ++s) ins4(sd[s], si[s], bd, bi_);
  }
  if (lane < 16) {
    size_t o = (((size_t)mq * NH + h) * TT + (t0 + lane)) * 4;
#pragma unroll
    for (int s = 0; s < 4; ++s) { pd[o + s] = bd[s]; pi[o + s] = bi_[s]; }
  }
}

// ---------------- merge M-quarter partial lists ----------------
__global__ void __launch_bounds__(256) topk_merge(
    const float* __restrict__ pd, const int* __restrict__ pi, int* __restrict__ idx)
{
  int g = blockIdx.x * 256 + threadIdx.x;
  float fd[4]; int fi[4];
#pragma unroll
  for (int s = 0; s < 4; ++s) { fd[s] = pd[(size_t)g * 4 + s]; fi[s] = pi[(size_t)g * 4 + s]; }
#pragma unroll
  for (int q = 1; q < MQ; ++q)
#pragma unroll
    for (int s = 0; s < 4; ++s)
      ins4(pd[(size_t)(q * NH * TT + g) * 4 + s], pi[(size_t)(q * NH * TT + g) * 4 + s], fd, fi);
#pragma unroll
  for (int s = 0; s < 4; ++s) idx[(size_t)g * 4 + s] = fi[s];
}

// ---------------- kNN attend ----------------
__global__ void __launch_bounds__(256) knn_attend(
    const char* __restrict__ qhi, const char* __restrict__ qlo,
    const float* __restrict__ attlast, const int* __restrict__ idx,
    const float* __restrict__ kstore, const float* __restrict__ vstore,
    float* __restrict__ vnew)
{
  int gw = (blockIdx.x * 256 + threadIdx.x) >> 6;
  int lane = threadIdx.x & 63;
  int h = gw >> 10, t = gw & 1023;
  int sw = ((lane >> 3) ^ (t & 7)) << 4;
  int o2 = (lane & 7) << 1;
  size_t rb = (size_t)t * 6144;
  size_t offq = rb + h * 128 + sw + o2;
  float q = bf16f(*(const unsigned short*)(qhi + offq)) + bf16f(*(const unsigned short*)(qlo + offq));
  size_t offk = offq + 2048;
  float k = bf16f(*(const unsigned short*)(qhi + offk)) + bf16f(*(const unsigned short*)(qlo + offk));
  size_t offv = offq + 4096;
  float v = bf16f(*(const unsigned short*)(qhi + offv)) + bf16f(*(const unsigned short*)(qlo + offv));
  float al = attlast[(h << 10) + t];
  bool sel = al >= (1.0f / 8192.0f);
  const int* ix = idx + ((size_t)h * TT + t) * 4;

  float attf[5], vf[5];
  attf[0] = wredsum(q * k) * 0.125f;
  vf[0] = v;
#pragma unroll
  for (int s = 1; s < 5; ++s) {
    int m = ix[s - 1];
    const float* kp = kstore + ((size_t)h * MM + m) * DD;
    const float* vp = vstore + ((size_t)h * MM + m) * DD;
    attf[s] = wredsum(q * kp[lane]) * 0.125f;
    vf[s] = vp[lane];
  }
  float mx = attf[0];
#pragma unroll
  for (int s = 1; s < 5; ++s) mx = fmaxf(mx, attf[s]);
  float wgt[5], sum = 0.f;
#pragma unroll
  for (int s = 0; s < 5; ++s) { wgt[s] = __expf(attf[s] - mx); sum += wgt[s]; }
  float inv = 1.0f / sum;
  float vals = 0.f;
#pragma unroll
  for (int s = 0; s < 5; ++s) vals = fmaf(wgt[s] * inv, vf[s], vals);
  float r = 0.5f * vals + 0.5f * v;
  vnew[(size_t)h * TT * DD + (size_t)t * DD + lane] = sel ? r : v;
}

// ---------------- vnew [h][j][c] f32 -> vnewT HL rows (h*64+c, K=1024) ----------------
__global__ void __launch_bounds__(256) transpose_vnew(
    const float* __restrict__ vnew, char* __restrict__ vThi, char* __restrict__ vTlo)
{
  int h = blockIdx.y, j0 = blockIdx.x * 64;
  __shared__ float lds[64][65];
  int tid = threadIdx.x;
#pragma unroll
  for (int rep = 0; rep < 16; ++rep) {
    int ii = tid + rep * 256;
    int j = ii >> 6, c = ii & 63;
    lds[j][c] = vnew[((size_t)(h << 10) + j0 + j) * 64 + c];
  }
  __syncthreads();
  int c = tid >> 2, jp = (tid & 3) * 16;
  int r = (h << 6) + c;
#pragma unroll
  for (int grp = 0; grp < 2; ++grp) {
    short8 hv, lv;
#pragma unroll
    for (int e = 0; e < 8; ++e) {
      float f = lds[jp + grp * 8 + e][c];
      unsigned hb = bf16rn(f);
      hv[e] = (short)hb;
      lv[e] = (short)bf16rn(f - bf16f(hb));
    }
    int chunk = (((jp >> 3) + grp) & 7) ^ (r & 7);
    size_t off = ((size_t)r * 1024 + j0) * 2 + (chunk << 4);
    *(short8*)(vThi + off) = hv;
    *(short8*)(vTlo + off) = lv;
  }
}

// ---------------- att(HL in att region) @ vnewT -> yhl ----------------
// 128x64 tile, 4 waves (2x2), wave 64x32
__global__ void __launch_bounds__(256) gemm_attv(
    const char* __restrict__ attB, const char* __restrict__ vThi, const char* __restrict__ vTlo,
    char* __restrict__ Yhi, char* __restrict__ Ylo)
{
  int h = blockIdx.y, m0 = blockIdx.x * 128;
  const char* aBase = attB + (size_t)h * 4194304;
  int tid = threadIdx.x, lane = tid & 63, w = tid >> 6;
  int wr = w >> 1, wc = w & 1;
  __shared__ __align__(16) char smem[49152];
  char* sAhi = smem;
  char* sAlo = smem + 16384;
  char* sBhi = smem + 32768;
  char* sBlo = smem + 40960;
  f32x4 acc[4][2];
#pragma unroll
  for (int i = 0; i < 4; ++i)
#pragma unroll
    for (int j = 0; j < 2; ++j) acc[i][j] = (f32x4){0.f, 0.f, 0.f, 0.f};
  int lr = lane & 15, lc = lane >> 4;
  for (int kb = 0; kb < 16; ++kb) {
    if (kb) __syncthreads();
#pragma unroll
    for (int c8 = 0; c8 < 4; ++c8) {
      int r8 = w * 32 + c8 * 8;
      stage_rows8(aBase + (size_t)(m0 + r8) * 4096 + (size_t)kb * 128, 4096, sAhi + r8 * 128, lane);
      stage_rows8(aBase + (size_t)(m0 + r8) * 4096 + 2048 + (size_t)kb * 128, 4096, sAlo + r8 * 128, lane);
    }
#pragma unroll
    for (int c8 = 0; c8 < 2; ++c8) {
      int r8 = w * 16 + c8 * 8;
      stage_rows8(vThi + (size_t)((h << 6) + r8) * 2048 + (size_t)kb * 128, 2048, sBhi + r8 * 128, lane);
      stage_rows8(vTlo + (size_t)((h << 6) + r8) * 2048 + (size_t)kb * 128, 2048, sBlo + r8 * 128, lane);
    }
    __syncthreads();
#pragma unroll
    for (int kh = 0; kh < 2; ++kh) {
      short8 ah[4], al[4], bh[2], bl[2];
#pragma unroll
      for (int f = 0; f < 4; ++f) {
        int ra = wr * 64 + f * 16 + lr;
        int ca = ((kh * 4 + lc) ^ (ra & 7)) << 4;
        ah[f] = *(const short8*)(sAhi + ra * 128 + ca);
        al[f] = *(const short8*)(sAlo + ra * 128 + ca);
      }
#pragma unroll
      for (int f = 0; f < 2; ++f) {
        int rbr = wc * 32 + f * 16 + lr;
        int cb = ((kh * 4 + lc) ^ (rbr & 7)) << 4;
        bh[f] = *(const short8*)(sBhi + rbr * 128 + cb);
        bl[f] = *(const short8*)(sBlo + rbr * 128 + cb);
      }
#pragma unroll
      for (int mi = 0; mi < 4; ++mi)
#pragma unroll
        for (int nj = 0; nj < 2; ++nj) {
          acc[mi][nj] = __builtin_amdgcn_mfma_f32_16x16x32_bf16(ah[mi], bh[nj], acc[mi][nj], 0, 0, 0);
          acc[mi][nj] = __builtin_amdgcn_mfma_f32_16x16x32_bf16(al[mi], bh[nj], acc[mi][nj], 0, 0, 0);
          acc[mi][nj] = __builtin_amdgcn_mfma_f32_16x16x32_bf16(ah[mi], bl[nj], acc[mi][nj], 0, 0, 0);
        }
    }
  }
#pragma unroll
  for (int mi = 0; mi < 4; ++mi)
#pragma unroll
    for (int nj = 0; nj < 2; ++nj)
#pragma unroll
      for (int r = 0; r < 4; ++r) {
        int m = m0 + wr * 64 + mi * 16 + lc * 4 + r;
        int n = (h << 6) + wc * 32 + nj * 16 + lr;
        float v = acc[mi][nj][r];
        unsigned hb = bf16rn(v);
        *(unsigned short*)(Yhi + hl_off(m, n, 1024)) = (unsigned short)hb;
        *(unsigned short*)(Ylo + hl_off(m, n, 1024)) = (unsigned short)bf16rn(v - bf16f(hb));
      }
}

// ---------------- reduce proj K-split partials + bias ----------------
__global__ void __launch_bounds__(256) reduce_bias(
    const float* __restrict__ p, const float* __restrict__ bias, float* __restrict__ out)
{
  int i4 = blockIdx.x * 256 + threadIdx.x;  // 262144 float4's
  const float4* P = (const float4*)p;
  float4 a = P[i4], b = P[i4 + 262144], c = P[i4 + 524288], d = P[i4 + 786432];
  float4 bb = ((const float4*)bias)[i4 & 255];
  float4 o;
  o.x = a.x + b.x + c.x + d.x + bb.x;
  o.y = a.y + b.y + c.y + d.y + bb.y;
  o.z = a.z + b.z + c.z + d.z + bb.z;
  o.w = a.w + b.w + c.w + d.w + bb.w;
  ((float4*)out)[i4] = o;
}

// ---------------- launch ----------------
extern "C" void kernel_launch(void* const* d_in, const int* in_sizes, int n_in,
                              void* d_out, int out_size, void* d_ws, size_t ws_size,
                              hipStream_t stream) {
  (void)in_sizes; (void)n_in; (void)out_size; (void)ws_size;
  const float* x  = (const float*)d_in[0];
  const float* Wa = (const float*)d_in[1];
  const float* ba = (const float*)d_in[2];
  const float* Wp = (const float*)d_in[3];
  const float* bp = (const float*)d_in[4];
  const float* Ks = (const float*)d_in[5];
  const float* Vs = (const float*)d_in[6];
  float* out = (float*)d_out;

  char* base = (char*)d_ws;
  // att region [0, 64 MiB): overlays xhl/wahl/khl (dead before logits) and pout (after att)
  char* xhi  = base;
  char* xlo  = base + 0x200000;
  char* wahi = base + 0x400000;
  char* walo = base + 0xA00000;
  char* khi  = base + 0x1000000;
  char* klo  = base + 0x2000000;
  float* att  = (float*)base;
  float* pout = (float*)base;
  char* tail = base + 0x4000000;
  char* qhi = tail;
  char* qlo = tail + 0x600000;
  float* attlast = (float*)(tail + 0xC00000);
  float* knorm   = (float*)(tail + 0xC10000);
  int*   idx     = (int*)(tail + 0xC90000);
  float* pd      = (float*)(tail + 0xCD0000);
  int*   pi      = (int*)(tail + 0xDD0000);
  float* vnew    = (float*)(tail + 0xED0000);
  char* vThi = tail + 0x12D0000;
  char* vTlo = tail + 0x14D0000;
  char* yhi  = tail + 0x16D0000;
  char* ylo  = tail + 0x18D0000;
  char* wphi = tail + 0x1AD0000;
  char* wplo = tail + 0x1CD0000;

  // 1) pre-split operands
  hipLaunchKernelGGL(convert_hl, dim3(512), dim3(256), 0, stream, x, xhi, xlo, 131072);
  hipLaunchKernelGGL(convert_hl, dim3(1536), dim3(256), 0, stream, Wa, wahi, walo, 393216);
  hipLaunchKernelGGL(convert_hl, dim3(512), dim3(256), 0, stream, Wp, wphi, wplo, 131072);
  hipLaunchKernelGGL(convert_kernel, dim3(NH * MM / 256), dim3(256), 0, stream, Ks, khi, klo, knorm);
  // 2) qkv = x @ Wa^T + ba  -> HL only
  hipLaunchKernelGGL(gemm_hl, dim3(24, 8, 1), dim3(256), 0, stream,
                     (const char*)xhi, (const char*)xlo, 2048, 0, 0,
                     (const char*)wahi, (const char*)walo, 2048, 0, 0,
                     0, 16, 0,
                     (float*)nullptr, 0LL, 0,
                     qhi, qlo, 3072,
                     ba, 1.0f, 0);
  // 3) top-4 over key store
  hipLaunchKernelGGL(topk_mfma, dim3(16 * 16 * MQ), dim3(256), 0, stream,
                     (const char*)qhi, (const char*)qlo, (const char*)khi, (const char*)klo,
                     knorm, pd, pi);
  hipLaunchKernelGGL(topk_merge, dim3(NH * TT / 256), dim3(256), 0, stream, pd, pi, idx);
  // 4) logits = q @ k^T / 8 (causal blocks only) -> f32 att
  hipLaunchKernelGGL(gemm_hl, dim3(8, 8, 16), dim3(256), 0, stream,
                     (const char*)qhi, (const char*)qlo, 6144, 0, 1,
                     (const char*)qhi, (const char*)qlo, 6144, 16, 1,
                     0, 1, 0,
                     att, 1048576LL, 1024,
                     (char*)nullptr, (char*)nullptr, 0,
                     (const float*)nullptr, 0.125f, 1);
  // 5) softmax -> HL in place + last row f32
  hipLaunchKernelGGL(softmax_causal, dim3(NH * TT / 4), dim3(256), 0, stream, att, attlast);
  // 6) kNN attend
  hipLaunchKernelGGL(knn_attend, dim3(NH * TT / 4), dim3(256), 0, stream,
                     (const char*)qhi, (const char*)qlo, attlast, idx, Ks, Vs, vnew);
  // 7) transpose vnew -> HL
  hipLaunchKernelGGL(transpose_vnew, dim3(16, 16), dim3(256), 0, stream, vnew, vThi, vTlo);
  // 8) y = att @ v_new -> yhl
  hipLaunchKernelGGL(gemm_attv, dim3(8, 16), dim3(256), 0, stream,
                     (const char*)att, (const char*)vThi, (const char*)vTlo, yhi, ylo);
  // 9) out = y @ Wp^T + bp  (K-split 4 + reduce)
  hipLaunchKernelGGL(gemm_hl, dim3(8, 8, 4), dim3(256), 0, stream,
                     (const char*)yhi, (const char*)ylo, 2048, 0, 0,
                     (const char*)wphi, (const char*)wplo, 2048, 0, 0,
                     0, 4, 4,
                     pout, 1048576LL, 1024,
                     (char*)nullptr, (char*)nullptr, 0,
                     (const float*)nullptr, 1.0f, 0);
  hipLaunchKernelGGL(reduce_bias, dim3(1024), dim3(256), 0, stream, pout, bp, out);
}

// Round 5
// 251.387 us; speedup vs baseline: 3.8666x; 1.1210x over previous
//
#include <hip/hip_runtime.h>
#include <math.h>

#define NH 16
#define TT 1024
#define CC 1024
#define DD 64
#define MM 8192
#define MQ 4
#define MQS (MM / MQ)

typedef __attribute__((ext_vector_type(8))) short short8;
typedef __attribute__((ext_vector_type(4))) float f32x4;

// ---------------- helpers ----------------
__device__ __forceinline__ float wredsum(float x) {
#pragma unroll
  for (int o = 32; o; o >>= 1) x += __shfl_xor(x, o);
  return x;
}
__device__ __forceinline__ float wredmax(float x) {
#pragma unroll
  for (int o = 32; o; o >>= 1) x = fmaxf(x, __shfl_xor(x, o));
  return x;
}
__device__ __forceinline__ unsigned int bf16rn(float x) {
  unsigned int u = __float_as_uint(x);
  return (u + 0x7fffu + ((u >> 16) & 1u)) >> 16;
}
__device__ __forceinline__ float bf16f(unsigned int h) {
  return __uint_as_float(h << 16);
}
// HL layout: element (r,k) of [R][K] matrix; 16B chunks swizzled by r&7 in each 64-elem block
__device__ __forceinline__ size_t hl_off(int r, int k, int K) {
  return (size_t)(r * K + (k & ~63)) * 2 + ((((k >> 3) & 7) ^ (r & 7)) << 4) + ((k & 7) << 1);
}

__device__ __forceinline__ void ins4(float d, int i, float vd[4], int vi[4]) {
  if (d < vd[3] || (d == vd[3] && i < vi[3])) {
    vd[3] = d; vi[3] = i;
#pragma unroll
    for (int s = 3; s > 0; --s) {
      bool sw = (vd[s] < vd[s - 1]) || (vd[s] == vd[s - 1] && vi[s] < vi[s - 1]);
      if (sw) {
        float td = vd[s]; vd[s] = vd[s - 1]; vd[s - 1] = td;
        int ti = vi[s]; vi[s] = vi[s - 1]; vi[s - 1] = ti;
      }
    }
  }
}

// ---------------- staging (global -> LDS direct) ----------------
__device__ __forceinline__ void stage_seg16(const char* gsrc, char* ldst, int lane) {
  __builtin_amdgcn_global_load_lds(
      (const __attribute__((address_space(1))) unsigned int*)(gsrc + lane * 16),
      (__attribute__((address_space(3))) unsigned int*)ldst, 16, 0, 0);
}
__device__ __forceinline__ void stage_seg4(const char* gsrc, char* ldst, int lane) {
  __builtin_amdgcn_global_load_lds(
      (const __attribute__((address_space(1))) unsigned int*)(gsrc + lane * 4),
      (__attribute__((address_space(3))) unsigned int*)ldst, 4, 0, 0);
}
__device__ __forceinline__ void stage_rows8(const char* gRow0, size_t gStride, char* lds, int lane) {
  __builtin_amdgcn_global_load_lds(
      (const __attribute__((address_space(1))) unsigned int*)(gRow0 + (size_t)(lane >> 3) * gStride + ((lane & 7) << 4)),
      (__attribute__((address_space(3))) unsigned int*)lds, 16, 0, 0);
}

// ---------------- convert f32 [R][1024] -> HL ----------------
__global__ void __launch_bounds__(256) convert_hl(
    const float* __restrict__ src, char* __restrict__ hi, char* __restrict__ lo, int nChunks)
{
  int gc = blockIdx.x * 256 + threadIdx.x;
  if (gc >= nChunks) return;
  int r = gc >> 7, c = gc & 127;
  const float* p = src + ((size_t)r << 10) + (c << 3);
  float4 f0 = *(const float4*)p;
  float4 f1 = *(const float4*)(p + 4);
  float f[8] = {f0.x, f0.y, f0.z, f0.w, f1.x, f1.y, f1.z, f1.w};
  short8 hv, lv;
#pragma unroll
  for (int e = 0; e < 8; ++e) {
    unsigned hb = bf16rn(f[e]);
    hv[e] = (short)hb;
    lv[e] = (short)bf16rn(f[e] - bf16f(hb));
  }
  size_t off = ((size_t)(r << 10) + ((c & ~7) << 3)) * 2 + (((c & 7) ^ (r & 7)) << 4);
  *(short8*)(hi + off) = hv;
  *(short8*)(lo + off) = lv;
}

// ---------------- K_store -> HL(K=64) + norms ----------------
__global__ void __launch_bounds__(256) convert_kernel(
    const float* __restrict__ ks, char* __restrict__ khi,
    char* __restrict__ klo, float* __restrict__ kn)
{
  int g = blockIdx.x * 256 + threadIdx.x;
  int m = g & (MM - 1);
  const float* src = ks + (size_t)g * DD;
  float nrm = 0.f;
  size_t rowb = (size_t)g * 128;
#pragma unroll
  for (int c = 0; c < 8; ++c) {
    float f[8];
#pragma unroll
    for (int j = 0; j < 8; ++j) {
      f[j] = src[c * 8 + j];
      nrm = fmaf(f[j], f[j], nrm);
    }
    uint4 hv, lv;
    unsigned int hw[4], lw[4];
#pragma unroll
    for (int p = 0; p < 4; ++p) {
      unsigned int h0 = bf16rn(f[2 * p]), h1 = bf16rn(f[2 * p + 1]);
      float r0 = f[2 * p] - bf16f(h0), r1 = f[2 * p + 1] - bf16f(h1);
      hw[p] = h0 | (h1 << 16);
      lw[p] = bf16rn(r0) | (bf16rn(r1) << 16);
    }
    hv.x = hw[0]; hv.y = hw[1]; hv.z = hw[2]; hv.w = hw[3];
    lv.x = lw[0]; lv.y = lw[1]; lv.z = lw[2]; lv.w = lw[3];
    size_t off = rowb + (size_t)(((c ^ (m & 7)) << 4));
    *(uint4*)(khi + off) = hv;
    *(uint4*)(klo + off) = lv;
  }
  kn[g] = nrm;
}

// ---------------- generic split-bf16 MFMA GEMM: C = scale*(A@B^T)+bias ----------------
__global__ void __launch_bounds__(256) gemm_hl(
    const char* __restrict__ Ahi, const char* __restrict__ Alo, int strideA, int aKb0, int aKbz,
    const char* __restrict__ Bhi, const char* __restrict__ Blo, int strideB, int bKb0, int bKbz,
    int kbBeg, int kbCnt, int kbzStep,
    float* __restrict__ Cf, long long czMul, int ldc,
    char* __restrict__ Chi, char* __restrict__ Clo, int Kc,
    const float* __restrict__ bias, float scale, int causal)
{
  int bx = blockIdx.x, by = blockIdx.y, z = blockIdx.z;
  int n0 = bx * 128, m0 = by * 128;
  if (causal && n0 > m0 + 127) return;
  int tid = threadIdx.x, lane = tid & 63, w = tid >> 6;
  int wr = w >> 1, wc = w & 1;
  __shared__ __align__(16) char smem[65536];
  char* sAhi = smem;
  char* sAlo = smem + 16384;
  char* sBhi = smem + 32768;
  char* sBlo = smem + 49152;
  f32x4 acc[4][4];
#pragma unroll
  for (int i = 0; i < 4; ++i)
#pragma unroll
    for (int j = 0; j < 4; ++j) acc[i][j] = (f32x4){0.f, 0.f, 0.f, 0.f};

  int kb0 = kbBeg + z * kbzStep;
  int lr = lane & 15, lc = lane >> 4;
  for (int i = 0; i < kbCnt; ++i) {
    int kbA = aKb0 + z * aKbz + kb0 + i;
    int kbB = bKb0 + z * bKbz + kb0 + i;
    if (i) __syncthreads();
#pragma unroll
    for (int c8 = 0; c8 < 4; ++c8) {
      int r8 = w * 32 + c8 * 8;
      stage_rows8(Ahi + (size_t)(m0 + r8) * strideA + (size_t)kbA * 128, strideA, sAhi + r8 * 128, lane);
      stage_rows8(Alo + (size_t)(m0 + r8) * strideA + (size_t)kbA * 128, strideA, sAlo + r8 * 128, lane);
      stage_rows8(Bhi + (size_t)(n0 + r8) * strideB + (size_t)kbB * 128, strideB, sBhi + r8 * 128, lane);
      stage_rows8(Blo + (size_t)(n0 + r8) * strideB + (size_t)kbB * 128, strideB, sBlo + r8 * 128, lane);
    }
    __syncthreads();
#pragma unroll
    for (int kh = 0; kh < 2; ++kh) {
      short8 ah[4], al[4], bh[4], bl[4];
#pragma unroll
      for (int f = 0; f < 4; ++f) {
        int ra = wr * 64 + f * 16 + lr;
        int ca = ((kh * 4 + lc) ^ (ra & 7)) << 4;
        ah[f] = *(const short8*)(sAhi + ra * 128 + ca);
        al[f] = *(const short8*)(sAlo + ra * 128 + ca);
        int rb = wc * 64 + f * 16 + lr;
        int cb = ((kh * 4 + lc) ^ (rb & 7)) << 4;
        bh[f] = *(const short8*)(sBhi + rb * 128 + cb);
        bl[f] = *(const short8*)(sBlo + rb * 128 + cb);
      }
#pragma unroll
      for (int mi = 0; mi < 4; ++mi)
#pragma unroll
        for (int nj = 0; nj < 4; ++nj) {
          acc[mi][nj] = __builtin_amdgcn_mfma_f32_16x16x32_bf16(ah[mi], bh[nj], acc[mi][nj], 0, 0, 0);
          acc[mi][nj] = __builtin_amdgcn_mfma_f32_16x16x32_bf16(al[mi], bh[nj], acc[mi][nj], 0, 0, 0);
          acc[mi][nj] = __builtin_amdgcn_mfma_f32_16x16x32_bf16(ah[mi], bl[nj], acc[mi][nj], 0, 0, 0);
        }
    }
  }
#pragma unroll
  for (int mi = 0; mi < 4; ++mi)
#pragma unroll
    for (int nj = 0; nj < 4; ++nj)
#pragma unroll
      for (int r = 0; r < 4; ++r) {
        int m = m0 + wr * 64 + mi * 16 + lc * 4 + r;
        int n = n0 + wc * 64 + nj * 16 + lr;
        float v = acc[mi][nj][r] * scale;
        if (bias) v += bias[n];
        if (Cf) Cf[(size_t)z * czMul + (size_t)m * ldc + n] = v;
        if (Chi) {
          unsigned hb = bf16rn(v);
          *(unsigned short*)(Chi + hl_off(m, n, Kc)) = (unsigned short)hb;
          *(unsigned short*)(Clo + hl_off(m, n, Kc)) = (unsigned short)bf16rn(v - bf16f(hb));
        }
      }
}

// ---------------- reduce qkv K-split partials + bias -> HL ----------------
__global__ void __launch_bounds__(256) reduce_qkv(
    const float* __restrict__ p, const float* __restrict__ bias,
    char* __restrict__ hi, char* __restrict__ lo)
{
  int gc = blockIdx.x * 256 + threadIdx.x;  // 1024*384 chunks of 8
  int t = gc / 384, c = gc - t * 384;
  const float* p0 = p + (size_t)t * 3072 + (c << 3);
  const float* p1 = p0 + (size_t)3072 * 1024;
  float4 a0 = *(const float4*)p0, a1 = *(const float4*)(p0 + 4);
  float4 b0 = *(const float4*)p1, b1 = *(const float4*)(p1 + 4);
  float4 bb0 = *(const float4*)(bias + (c << 3));
  float4 bb1 = *(const float4*)(bias + (c << 3) + 4);
  float f[8] = {a0.x + b0.x + bb0.x, a0.y + b0.y + bb0.y,
                a0.z + b0.z + bb0.z, a0.w + b0.w + bb0.w,
                a1.x + b1.x + bb1.x, a1.y + b1.y + bb1.y,
                a1.z + b1.z + bb1.z, a1.w + b1.w + bb1.w};
  short8 hv, lv;
#pragma unroll
  for (int e = 0; e < 8; ++e) {
    unsigned hb = bf16rn(f[e]);
    hv[e] = (short)hb;
    lv[e] = (short)bf16rn(f[e] - bf16f(hb));
  }
  size_t off = ((size_t)t * 3072 + ((c & ~7) << 3)) * 2 + (((c & 7) ^ (t & 7)) << 4);
  *(short8*)(hi + off) = hv;
  *(short8*)(lo + off) = lv;
}

// ---------------- causal softmax; writes HL in place + f32 last row ----------------
__global__ void __launch_bounds__(256) softmax_causal(float* __restrict__ att,
                                                      float* __restrict__ attlast) {
  int gw = (blockIdx.x * 256 + threadIdx.x) >> 6;
  int lane = threadIdx.x & 63;
  int h = gw >> 10, i = gw & 1023;
  float* row = att + ((size_t)h << 20) + ((size_t)i << 10);
  float e[16];
  float mx = -INFINITY;
#pragma unroll
  for (int c = 0; c < 16; ++c) {
    int j = lane + (c << 6);
    float xx = (j <= i) ? row[j] : -INFINITY;
    e[c] = xx;
    mx = fmaxf(mx, xx);
  }
  mx = wredmax(mx);
  float sum = 0.f;
#pragma unroll
  for (int c = 0; c < 16; ++c) {
    int j = lane + (c << 6);
    float v = (j <= i) ? __expf(e[c] - mx) : 0.f;
    e[c] = v;
    sum += v;
  }
  sum = wredsum(sum);
  float inv = 1.0f / sum;
  char* rowb = (char*)row;
  int sw = ((lane >> 3) ^ (i & 7)) << 4;
  int o2 = (lane & 7) << 1;
#pragma unroll
  for (int c = 0; c < 16; ++c) {
    float v = e[c] * inv;
    unsigned hb = bf16rn(v);
    unsigned lb = bf16rn(v - bf16f(hb));
    *(unsigned short*)(rowb + c * 128 + sw + o2) = (unsigned short)hb;
    *(unsigned short*)(rowb + 2048 + c * 128 + sw + o2) = (unsigned short)lb;
    if (i == 1023) attlast[(h << 10) + lane + (c << 6)] = v;
  }
}

// ---------------- MFMA distance + top-4 (packed-index candidates) ----------------
#define BUFB 16640
__global__ void __launch_bounds__(256, 4) topk_mfma(
    const char* __restrict__ qhi, const char* __restrict__ qlo,
    const char* __restrict__ khi, const char* __restrict__ klo,
    const float* __restrict__ knorm, float* __restrict__ pd, int* __restrict__ pi)
{
  int bid = blockIdx.x;
  int h = bid & 15, ttile = (bid >> 4) & 15, mq = bid >> 8;
  int tid = threadIdx.x, lane = tid & 63, w = tid >> 6;
  int t0 = ttile * 64 + w * 16;
  __shared__ __align__(16) char smem[2 * BUFB];

  short8 bhi[2], blo[2];
  {
    int t = t0 + (lane & 15);
    size_t rb = (size_t)t * 6144 + 2048 + h * 128;
#pragma unroll
    for (int kh = 0; kh < 2; ++kh) {
      int chunk = kh * 4 + (lane >> 4);
      size_t off = rb + ((chunk ^ (t & 7)) << 4);
      bhi[kh] = *(const short8*)(qhi + off);
      blo[kh] = *(const short8*)(qlo + off);
    }
  }

  const char* ghi = khi + ((size_t)h * MM + (size_t)mq * MQS) * 128;
  const char* glo = klo + ((size_t)h * MM + (size_t)mq * MQS) * 128;
  const char* gkn = (const char*)(knorm + (size_t)h * MM + (size_t)mq * MQS);

  // bd: packed floats (d2 with 4-bit local idx in mantissa LSBs), ascending
  float bd[4] = {3.0e38f, 3.0e38f, 3.0e38f, 3.0e38f};
  int   bi_[4] = {-1, -1, -1, -1};

  {
    char* nb = smem;
#pragma unroll
    for (int i2 = 0; i2 < 4; ++i2) {
      int s = w * 4 + i2;
      const char* src = (s < 8) ? (ghi + s * 1024) : (glo + (s - 8) * 1024);
      stage_seg16(src, nb + s * 1024, lane);
    }
    if (w == 0) stage_seg4(gkn, nb + 16384, lane);
  }
  __syncthreads();

  int buf = 0;
  const int NIT = MQS / 64;
  for (int it = 0; it < NIT; ++it) {
    char* cb = smem + buf * BUFB;
    if (it < NIT - 1) {
      char* nb = smem + (buf ^ 1) * BUFB;
      const char* bh = ghi + (size_t)(it + 1) * 8192;
      const char* bl = glo + (size_t)(it + 1) * 8192;
#pragma unroll
      for (int i2 = 0; i2 < 4; ++i2) {
        int s = w * 4 + i2;
        const char* src = (s < 8) ? (bh + s * 1024) : (bl + (s - 8) * 1024);
        stage_seg16(src, nb + s * 1024, lane);
      }
      if (w == 0) stage_seg4(gkn + (size_t)(it + 1) * 256, nb + 16384, lane);
    }

    f32x4 acc[4];
#pragma unroll
    for (int ms = 0; ms < 4; ++ms) acc[ms] = (f32x4){0.f, 0.f, 0.f, 0.f};
#pragma unroll
    for (int ms = 0; ms < 4; ++ms) {
      int mloc = ms * 16 + (lane & 15);
      short8 ah[2], al[2];
#pragma unroll
      for (int kh = 0; kh < 2; ++kh) {
        int c = kh * 4 + (lane >> 4);
        int off = mloc * 128 + (((c ^ (mloc & 7)) << 4));
        ah[kh] = *(const short8*)(cb + off);
        al[kh] = *(const short8*)(cb + 8192 + off);
      }
#pragma unroll
      for (int kh = 0; kh < 2; ++kh) {
        acc[ms] = __builtin_amdgcn_mfma_f32_16x16x32_bf16(ah[kh], bhi[kh], acc[ms], 0, 0, 0);
        acc[ms] = __builtin_amdgcn_mfma_f32_16x16x32_bf16(al[kh], bhi[kh], acc[ms], 0, 0, 0);
        acc[ms] = __builtin_amdgcn_mfma_f32_16x16x32_bf16(ah[kh], blo[kh], acc[ms], 0, 0, 0);
      }
    }

    f32x4 knv[4];
#pragma unroll
    for (int ms = 0; ms < 4; ++ms)
      knv[ms] = *(const f32x4*)(cb + 16384 + (ms * 16 + ((lane >> 4) << 2)) * 4);

    // packed candidates: d2 with local idx embedded in 4 LSBs
    float pf[16];
#pragma unroll
    for (int ms = 0; ms < 4; ++ms)
#pragma unroll
      for (int r = 0; r < 4; ++r) {
        float d2 = fmaf(-2.0f, acc[ms][r], knv[ms][r]);
        unsigned u = __float_as_uint(d2);
        pf[ms * 4 + r] = __uint_as_float((u & ~15u) | (unsigned)(ms * 4 + r));
      }
    float mn = pf[0];
#pragma unroll
    for (int c = 1; c < 16; ++c) mn = fminf(mn, pf[c]);

    int mg0 = mq * MQS + it * 64 + ((lane >> 4) << 2);
    while (mn < bd[3]) {
      unsigned pb = __float_as_uint(mn);
      int cl = pb & 15;
      int m = mg0 + ((cl & 12) << 2) + (cl & 3);
      bd[3] = mn; bi_[3] = m;
#pragma unroll
      for (int s = 3; s > 0; --s) {
        if (bd[s] < bd[s - 1]) {
          float td = bd[s]; bd[s] = bd[s - 1]; bd[s - 1] = td;
          int ti = bi_[s]; bi_[s] = bi_[s - 1]; bi_[s - 1] = ti;
        }
      }
#pragma unroll
      for (int c2 = 0; c2 < 16; ++c2)
        if (pf[c2] == mn) pf[c2] = 3.0e38f;
      mn = pf[0];
#pragma unroll
      for (int c2 = 1; c2 < 16; ++c2) mn = fminf(mn, pf[c2]);
    }

    __syncthreads();
    buf ^= 1;
  }

  // merge across the 4 lane-groups holding the same t (lex on packed d, then idx)
#pragma unroll
  for (int st = 16; st <= 32; st <<= 1) {
    float sd[4]; int si[4];
#pragma unroll
    for (int s = 0; s < 4; ++s) {
      sd[s] = __shfl_xor(bd[s], st);
      si[s] = __shfl_xor(bi_[s], st);
    }
#pragma unroll
    for (int s = 0; s < 4; ++s) ins4(sd[s], si[s], bd, bi_);
  }
  if (lane < 16) {
    size_t o = (((size_t)mq * NH + h) * TT + (t0 + lane)) * 4;
#pragma unroll
    for (int s = 0; s < 4; ++s) { pd[o + s] = bd[s]; pi[o + s] = bi_[s]; }
  }
}

// ---------------- merge M-quarter partial lists ----------------
__global__ void __launch_bounds__(256) topk_merge(
    const float* __restrict__ pd, const int* __restrict__ pi, int* __restrict__ idx)
{
  int g = blockIdx.x * 256 + threadIdx.x;
  float fd[4]; int fi[4];
#pragma unroll
  for (int s = 0; s < 4; ++s) { fd[s] = pd[(size_t)g * 4 + s]; fi[s] = pi[(size_t)g * 4 + s]; }
#pragma unroll
  for (int q = 1; q < MQ; ++q)
#pragma unroll
    for (int s = 0; s < 4; ++s)
      ins4(pd[(size_t)(q * NH * TT + g) * 4 + s], pi[(size_t)(q * NH * TT + g) * 4 + s], fd, fi);
#pragma unroll
  for (int s = 0; s < 4; ++s) idx[(size_t)g * 4 + s] = fi[s];
}

// ---------------- kNN attend ----------------
__global__ void __launch_bounds__(256) knn_attend(
    const char* __restrict__ qhi, const char* __restrict__ qlo,
    const float* __restrict__ attlast, const int* __restrict__ idx,
    const float* __restrict__ kstore, const float* __restrict__ vstore,
    float* __restrict__ vnew)
{
  int gw = (blockIdx.x * 256 + threadIdx.x) >> 6;
  int lane = threadIdx.x & 63;
  int h = gw >> 10, t = gw & 1023;
  int sw = ((lane >> 3) ^ (t & 7)) << 4;
  int o2 = (lane & 7) << 1;
  size_t rb = (size_t)t * 6144;
  size_t offq = rb + h * 128 + sw + o2;
  float q = bf16f(*(const unsigned short*)(qhi + offq)) + bf16f(*(const unsigned short*)(qlo + offq));
  size_t offk = offq + 2048;
  float k = bf16f(*(const unsigned short*)(qhi + offk)) + bf16f(*(const unsigned short*)(qlo + offk));
  size_t offv = offq + 4096;
  float v = bf16f(*(const unsigned short*)(qhi + offv)) + bf16f(*(const unsigned short*)(qlo + offv));
  float al = attlast[(h << 10) + t];
  bool sel = al >= (1.0f / 8192.0f);
  const int* ix = idx + ((size_t)h * TT + t) * 4;

  float attf[5], vf[5];
  attf[0] = wredsum(q * k) * 0.125f;
  vf[0] = v;
#pragma unroll
  for (int s = 1; s < 5; ++s) {
    int m = ix[s - 1];
    const float* kp = kstore + ((size_t)h * MM + m) * DD;
    const float* vp = vstore + ((size_t)h * MM + m) * DD;
    attf[s] = wredsum(q * kp[lane]) * 0.125f;
    vf[s] = vp[lane];
  }
  float mx = attf[0];
#pragma unroll
  for (int s = 1; s < 5; ++s) mx = fmaxf(mx, attf[s]);
  float wgt[5], sum = 0.f;
#pragma unroll
  for (int s = 0; s < 5; ++s) { wgt[s] = __expf(attf[s] - mx); sum += wgt[s]; }
  float inv = 1.0f / sum;
  float vals = 0.f;
#pragma unroll
  for (int s = 0; s < 5; ++s) vals = fmaf(wgt[s] * inv, vf[s], vals);
  float r = 0.5f * vals + 0.5f * v;
  vnew[(size_t)h * TT * DD + (size_t)t * DD + lane] = sel ? r : v;
}

// ---------------- vnew [h][j][c] f32 -> vnewT HL rows (h*64+c, K=1024) ----------------
__global__ void __launch_bounds__(256) transpose_vnew(
    const float* __restrict__ vnew, char* __restrict__ vThi, char* __restrict__ vTlo)
{
  int h = blockIdx.y, j0 = blockIdx.x * 64;
  __shared__ float lds[64][65];
  int tid = threadIdx.x;
#pragma unroll
  for (int rep = 0; rep < 16; ++rep) {
    int ii = tid + rep * 256;
    int j = ii >> 6, c = ii & 63;
    lds[j][c] = vnew[((size_t)(h << 10) + j0 + j) * 64 + c];
  }
  __syncthreads();
  int c = tid >> 2, jp = (tid & 3) * 16;
  int r = (h << 6) + c;
#pragma unroll
  for (int grp = 0; grp < 2; ++grp) {
    short8 hv, lv;
#pragma unroll
    for (int e = 0; e < 8; ++e) {
      float f = lds[jp + grp * 8 + e][c];
      unsigned hb = bf16rn(f);
      hv[e] = (short)hb;
      lv[e] = (short)bf16rn(f - bf16f(hb));
    }
    int chunk = (((jp >> 3) + grp) & 7) ^ (r & 7);
    size_t off = ((size_t)r * 1024 + j0) * 2 + (chunk << 4);
    *(short8*)(vThi + off) = hv;
    *(short8*)(vTlo + off) = lv;
  }
}

// ---------------- att(HL) @ vnewT -> yhl ----------------
__global__ void __launch_bounds__(256) gemm_attv(
    const char* __restrict__ attB, const char* __restrict__ vThi, const char* __restrict__ vTlo,
    char* __restrict__ Yhi, char* __restrict__ Ylo)
{
  int h = blockIdx.y, m0 = blockIdx.x * 128;
  const char* aBase = attB + (size_t)h * 4194304;
  int tid = threadIdx.x, lane = tid & 63, w = tid >> 6;
  int wr = w >> 1, wc = w & 1;
  __shared__ __align__(16) char smem[49152];
  char* sAhi = smem;
  char* sAlo = smem + 16384;
  char* sBhi = smem + 32768;
  char* sBlo = smem + 40960;
  f32x4 acc[4][2];
#pragma unroll
  for (int i = 0; i < 4; ++i)
#pragma unroll
    for (int j = 0; j < 2; ++j) acc[i][j] = (f32x4){0.f, 0.f, 0.f, 0.f};
  int lr = lane & 15, lc = lane >> 4;
  for (int kb = 0; kb < 16; ++kb) {
    if (kb) __syncthreads();
#pragma unroll
    for (int c8 = 0; c8 < 4; ++c8) {
      int r8 = w * 32 + c8 * 8;
      stage_rows8(aBase + (size_t)(m0 + r8) * 4096 + (size_t)kb * 128, 4096, sAhi + r8 * 128, lane);
      stage_rows8(aBase + (size_t)(m0 + r8) * 4096 + 2048 + (size_t)kb * 128, 4096, sAlo + r8 * 128, lane);
    }
#pragma unroll
    for (int c8 = 0; c8 < 2; ++c8) {
      int r8 = w * 16 + c8 * 8;
      stage_rows8(vThi + (size_t)((h << 6) + r8) * 2048 + (size_t)kb * 128, 2048, sBhi + r8 * 128, lane);
      stage_rows8(vTlo + (size_t)((h << 6) + r8) * 2048 + (size_t)kb * 128, 2048, sBlo + r8 * 128, lane);
    }
    __syncthreads();
#pragma unroll
    for (int kh = 0; kh < 2; ++kh) {
      short8 ah[4], al[4], bh[2], bl[2];
#pragma unroll
      for (int f = 0; f < 4; ++f) {
        int ra = wr * 64 + f * 16 + lr;
        int ca = ((kh * 4 + lc) ^ (ra & 7)) << 4;
        ah[f] = *(const short8*)(sAhi + ra * 128 + ca);
        al[f] = *(const short8*)(sAlo + ra * 128 + ca);
      }
#pragma unroll
      for (int f = 0; f < 2; ++f) {
        int rbr = wc * 32 + f * 16 + lr;
        int cb = ((kh * 4 + lc) ^ (rbr & 7)) << 4;
        bh[f] = *(const short8*)(sBhi + rbr * 128 + cb);
        bl[f] = *(const short8*)(sBlo + rbr * 128 + cb);
      }
#pragma unroll
      for (int mi = 0; mi < 4; ++mi)
#pragma unroll
        for (int nj = 0; nj < 2; ++nj) {
          acc[mi][nj] = __builtin_amdgcn_mfma_f32_16x16x32_bf16(ah[mi], bh[nj], acc[mi][nj], 0, 0, 0);
          acc[mi][nj] = __builtin_amdgcn_mfma_f32_16x16x32_bf16(al[mi], bh[nj], acc[mi][nj], 0, 0, 0);
          acc[mi][nj] = __builtin_amdgcn_mfma_f32_16x16x32_bf16(ah[mi], bl[nj], acc[mi][nj], 0, 0, 0);
        }
    }
  }
#pragma unroll
  for (int mi = 0; mi < 4; ++mi)
#pragma unroll
    for (int nj = 0; nj < 2; ++nj)
#pragma unroll
      for (int r = 0; r < 4; ++r) {
        int m = m0 + wr * 64 + mi * 16 + lc * 4 + r;
        int n = (h << 6) + wc * 32 + nj * 16 + lr;
        float v = acc[mi][nj][r];
        unsigned hb = bf16rn(v);
        *(unsigned short*)(Yhi + hl_off(m, n, 1024)) = (unsigned short)hb;
        *(unsigned short*)(Ylo + hl_off(m, n, 1024)) = (unsigned short)bf16rn(v - bf16f(hb));
      }
}

// ---------------- reduce proj K-split partials + bias ----------------
__global__ void __launch_bounds__(256) reduce_bias(
    const float* __restrict__ p, const float* __restrict__ bias, float* __restrict__ out)
{
  int i4 = blockIdx.x * 256 + threadIdx.x;
  const float4* P = (const float4*)p;
  float4 a = P[i4], b = P[i4 + 262144], c = P[i4 + 524288], d = P[i4 + 786432];
  float4 bb = ((const float4*)bias)[i4 & 255];
  float4 o;
  o.x = a.x + b.x + c.x + d.x + bb.x;
  o.y = a.y + b.y + c.y + d.y + bb.y;
  o.z = a.z + b.z + c.z + d.z + bb.z;
  o.w = a.w + b.w + c.w + d.w + bb.w;
  ((float4*)out)[i4] = o;
}

// ---------------- launch ----------------
extern "C" void kernel_launch(void* const* d_in, const int* in_sizes, int n_in,
                              void* d_out, int out_size, void* d_ws, size_t ws_size,
                              hipStream_t stream) {
  (void)in_sizes; (void)n_in; (void)out_size; (void)ws_size;
  const float* x  = (const float*)d_in[0];
  const float* Wa = (const float*)d_in[1];
  const float* ba = (const float*)d_in[2];
  const float* Wp = (const float*)d_in[3];
  const float* bp = (const float*)d_in[4];
  const float* Ks = (const float*)d_in[5];
  const float* Vs = (const float*)d_in[6];
  float* out = (float*)d_out;

  char* base = (char*)d_ws;
  char* xhi  = base;
  char* xlo  = base + 0x200000;
  char* wahi = base + 0x400000;
  char* walo = base + 0xA00000;
  char* khi  = base + 0x1000000;
  char* klo  = base + 0x2000000;
  float* qkvp = (float*)(base + 0x1000000);  // qkv partials overlay khl (written later)
  float* att  = (float*)base;
  float* pout = (float*)base;
  char* tail = base + 0x4000000;
  char* qhi = tail;
  char* qlo = tail + 0x600000;
  float* attlast = (float*)(tail + 0xC00000);
  float* knorm   = (float*)(tail + 0xC10000);
  int*   idx     = (int*)(tail + 0xC90000);
  float* pd      = (float*)(tail + 0xCD0000);
  int*   pi      = (int*)(tail + 0xDD0000);
  float* vnew    = (float*)(tail + 0xED0000);
  char* vThi = tail + 0x12D0000;
  char* vTlo = tail + 0x14D0000;
  char* yhi  = tail + 0x16D0000;
  char* ylo  = tail + 0x18D0000;
  char* wphi = tail + 0x1AD0000;
  char* wplo = tail + 0x1CD0000;

  // 1) convert x, Wa
  hipLaunchKernelGGL(convert_hl, dim3(512), dim3(256), 0, stream, x, xhi, xlo, 131072);
  hipLaunchKernelGGL(convert_hl, dim3(1536), dim3(256), 0, stream, Wa, wahi, walo, 393216);
  // 2) qkv = x @ Wa^T (K-split 2, f32 partials into khl region)
  hipLaunchKernelGGL(gemm_hl, dim3(24, 8, 2), dim3(256), 0, stream,
                     (const char*)xhi, (const char*)xlo, 2048, 0, 0,
                     (const char*)wahi, (const char*)walo, 2048, 0, 0,
                     0, 8, 8,
                     qkvp, 3145728LL, 3072,
                     (char*)nullptr, (char*)nullptr, 0,
                     (const float*)nullptr, 1.0f, 0);
  // 3) reduce partials + bias -> qhl
  hipLaunchKernelGGL(reduce_qkv, dim3(1536), dim3(256), 0, stream, qkvp, ba, qhi, qlo);
  // 4) K_store -> khl + norms (overwrites partials), Wp -> hl
  hipLaunchKernelGGL(convert_kernel, dim3(NH * MM / 256), dim3(256), 0, stream, Ks, khi, klo, knorm);
  hipLaunchKernelGGL(convert_hl, dim3(512), dim3(256), 0, stream, Wp, wphi, wplo, 131072);
  // 5) top-4 over key store
  hipLaunchKernelGGL(topk_mfma, dim3(16 * 16 * MQ), dim3(256), 0, stream,
                     (const char*)qhi, (const char*)qlo, (const char*)khi, (const char*)klo,
                     knorm, pd, pi);
  hipLaunchKernelGGL(topk_merge, dim3(NH * TT / 256), dim3(256), 0, stream, pd, pi, idx);
  // 6) logits = q @ k^T / 8 (causal blocks only) -> f32 att
  hipLaunchKernelGGL(gemm_hl, dim3(8, 8, 16), dim3(256), 0, stream,
                     (const char*)qhi, (const char*)qlo, 6144, 0, 1,
                     (const char*)qhi, (const char*)qlo, 6144, 16, 1,
                     0, 1, 0,
                     att, 1048576LL, 1024,
                     (char*)nullptr, (char*)nullptr, 0,
                     (const float*)nullptr, 0.125f, 1);
  // 7) softmax -> HL in place + last row f32
  hipLaunchKernelGGL(softmax_causal, dim3(NH * TT / 4), dim3(256), 0, stream, att, attlast);
  // 8) kNN attend
  hipLaunchKernelGGL(knn_attend, dim3(NH * TT / 4), dim3(256), 0, stream,
                     (const char*)qhi, (const char*)qlo, attlast, idx, Ks, Vs, vnew);
  // 9) transpose vnew -> HL
  hipLaunchKernelGGL(transpose_vnew, dim3(16, 16), dim3(256), 0, stream, vnew, vThi, vTlo);
  // 10) y = att @ v_new -> yhl
  hipLaunchKernelGGL(gemm_attv, dim3(8, 16), dim3(256), 0, stream,
                     (const char*)att, (const char*)vThi, (const char*)vTlo, yhi, ylo);
  // 11) out = y @ Wp^T + bp (K-split 4 + reduce)
  hipLaunchKernelGGL(gemm_hl, dim3(8, 8, 4), dim3(256), 0, stream,
                     (const char*)yhi, (const char*)ylo, 2048, 0, 0,
                     (const char*)wphi, (const char*)wplo, 2048, 0, 0,
                     0, 4, 4,
                     pout, 1048576LL, 1024,
                     (char*)nullptr, (char*)nullptr, 0,
                     (const float*)nullptr, 1.0f, 0);
  hipLaunchKernelGGL(reduce_bias, dim3(1024), dim3(256), 0, stream, pout, bp, out);
}